// Round 5
// baseline (2851.855 us; speedup 1.0000x reference)
//
#include <hip/hip_runtime.h>
#include <hip/hip_bf16.h>

typedef __bf16 bfx8 __attribute__((ext_vector_type(8)));
typedef __bf16 bfx4 __attribute__((ext_vector_type(4)));
typedef float f32x4 __attribute__((ext_vector_type(4)));

#define MFMA __builtin_amdgcn_mfma_f32_16x16x32_bf16

// Dims: S=32 T=32 B=512 H=1024 E=256 A=1024 VS=64 VT=70 START=1
// Separate-launch structure (cooperative grid.sync measured ~35us/sync).
// Weights pre-swizzled fragment-major (64 lanes x 16B per 16x32 fragment).
// gru_step v5: grid (32 j, 16 m) x 256 thr. NO A-staging: all operands
// (hb_in, Adec, emb, W) read direct from global (L2-resident); LDS only
// for the 24KB f32 gi/gh handoffs; ONE barrier per kernel. Encoder t=0
// skips gh entirely (h0=0 -> gh=bias). k_hl v2: de-staged, 0 LDS,
// 0 barriers. k_encpart: XCD-swizzled, A double-buffered 32KB K-chunks.

__device__ __attribute__((aligned(256))) float  g_h[512 * 1024];
__device__ __attribute__((aligned(256))) float  g_hpart[512 * 1024];
__device__ __attribute__((aligned(256))) __bf16 g_hb[2][512 * 1024];
__device__ __attribute__((aligned(256))) __bf16 g_Adec[512 * 1280];
__device__ __attribute__((aligned(256))) __bf16 g_enc_ops[(size_t)32 * 512 * 1024];
__device__ __attribute__((aligned(256))) __bf16 g_enc_part[(size_t)32 * 512 * 1024];
__device__ __attribute__((aligned(256))) __bf16 g_sWhhe[(size_t)3072 * 1024];   // fragment-major
__device__ __attribute__((aligned(256))) __bf16 g_sWihe[(size_t)3072 * 256];
__device__ __attribute__((aligned(256))) __bf16 g_sWhhd[(size_t)3072 * 1024];
__device__ __attribute__((aligned(256))) __bf16 g_sWihd[(size_t)3072 * 1280];
__device__ __attribute__((aligned(256))) __bf16 g_sWattnA[(size_t)1024 * 1024];
__device__ __attribute__((aligned(256))) __bf16 g_sWattnB[(size_t)1024 * 1024]; // W_attn[H:2H] frag-major
__device__ __attribute__((aligned(256))) __bf16 g_sWout[(size_t)128 * 1024];
__device__ __attribute__((aligned(256))) __bf16 g_embs[64 * 256];
__device__ __attribute__((aligned(256))) __bf16 g_embt[70 * 256];

__device__ __forceinline__ float fast_tanh(float x) {
    float cx = fminf(fmaxf(x, -15.f), 15.f);
    float e = __expf(-2.f * cx);
    return (1.f - e) / (1.f + e);
}

// ---------------------------------------------------------------------------
__global__ void k_cvt(const float* __restrict__ src, __bf16* __restrict__ dst,
                      int n4)
{
    int i = blockIdx.x * 256 + threadIdx.x;
    if (i >= n4) return;
    float4 v = ((const float4*)src)[i];
    __bf16 o[4] = {(__bf16)v.x, (__bf16)v.y, (__bf16)v.z, (__bf16)v.w};
    *(ushort2*)(dst + 4 * i) = *(ushort2*)o;
    *(ushort2*)(dst + 4 * i + 2) = *(ushort2*)(o + 2);
}

// Row-major f32 W[R][K] -> fragment-major bf16.
__global__ void swz_rm(const float* __restrict__ W, __bf16* __restrict__ out,
                       int nK, int total)
{
    int gid = blockIdx.x * 256 + threadIdx.x;
    if (gid >= total) return;
    int F = gid >> 6, L = gid & 63;
    int t = F / nK, c = F - t * nK;
    int K = nK * 32;
    const float* s = W + (size_t)(t * 16 + (L & 15)) * K + c * 32 + (L >> 4) * 8;
    __bf16 o[8];
#pragma unroll
    for (int u = 0; u < 8; u++) o[u] = (__bf16)s[u];
    *(uint4*)(out + (size_t)gid * 8) = *(uint4*)o;
}

// Column-gather: logical W'[n][k] = W[k*ldsrc + n]; n>=nguard -> 0.
__global__ void swz_cm(const float* __restrict__ W, __bf16* __restrict__ out,
                       int nK, int ldsrc, int nguard, int total)
{
    int gid = blockIdx.x * 256 + threadIdx.x;
    if (gid >= total) return;
    int F = gid >> 6, L = gid & 63;
    int t = F / nK, c = F - t * nK;
    int n = t * 16 + (L & 15);
    int k = c * 32 + (L >> 4) * 8;
    __bf16 o[8];
#pragma unroll
    for (int u = 0; u < 8; u++)
        o[u] = (n < nguard) ? (__bf16)W[(size_t)(k + u) * ldsrc + n] : (__bf16)0.f;
    *(uint4*)(out + (size_t)gid * 8) = *(uint4*)o;
}

__global__ void k_init(float* __restrict__ out)
{
    int idx = blockIdx.x * 256 + threadIdx.x;
    if (idx < 512 * 1024) { g_h[idx] = 0.f; g_hb[0][idx] = (__bf16)0.f; }
    if (idx < 512 * 70) out[idx] = (idx % 70 == 1) ? 1.f : 0.f;
}

// ---------------------------------------------------------------------------
// k_encpart: enc_part = enc_ops(16384x1024) @ W_attn[H:2H]^T (frag-major).
// 1024 blocks x 512 thr, XCD-swizzled: XCD r owns m-tiles [r*32, r*32+32)
// with all 4 n-blocks co-located -> A-tile HBM-fetched once per XCD.
// A staged in 4 double-buffered 32KB K-chunks (2 blocks/CU).
// ---------------------------------------------------------------------------
__global__ __launch_bounds__(512, 4) void k_encpart(
    const __bf16* __restrict__ Amat, const __bf16* __restrict__ sW,
    __bf16* __restrict__ Cout)
{
    __shared__ __bf16 sA[2][64 * 256];   // 2 x 32 KB
    const int tid = threadIdx.x;
    const int w = tid >> 6, lane = tid & 63;
    const int r15 = lane & 15, q = lane >> 4;
    const int sw = (blockIdx.x & 7) * 128 + (blockIdx.x >> 3);
    const int nx = sw & 3;
    const int n0 = nx * 256, m0 = (sw >> 2) * 64;

    int sr[4], sv[4], so[4];
#pragma unroll
    for (int i = 0; i < 4; i++) {
        int lin = tid + i * 512;
        sr[i] = lin >> 5;
        sv[i] = lin & 31;
        so[i] = (sr[i] * 32 + (sv[i] ^ (sr[i] & 7))) * 8;
    }

    uint4 regs[4];
#pragma unroll
    for (int i = 0; i < 4; i++)
        regs[i] = *(const uint4*)(Amat + (size_t)(m0 + sr[i]) * 1024 + sv[i] * 8);
#pragma unroll
    for (int i = 0; i < 4; i++)
        *(uint4*)(&sA[0][so[i]]) = regs[i];
    __syncthreads();

    const int xk = r15 & 7;
    f32x4 acc[2][4];
#pragma unroll
    for (int nn = 0; nn < 2; nn++)
#pragma unroll
        for (int mf = 0; mf < 4; mf++) acc[nn][mf] = (f32x4){0.f, 0.f, 0.f, 0.f};

    const __bf16* wp0 = sW + ((size_t)(nx * 16 + w * 2) * 32) * 512 + lane * 8;
    const __bf16* wp1 = wp0 + 32 * 512;
    const int ar0 = r15 * 256;
    const int ar1 = (16 + r15) * 256;
    const int ar2 = (32 + r15) * 256;
    const int ar3 = (48 + r15) * 256;

    for (int kc = 0; kc < 4; kc++) {
        if (kc < 3) {
#pragma unroll
            for (int i = 0; i < 4; i++)
                regs[i] = *(const uint4*)(Amat + (size_t)(m0 + sr[i]) * 1024 +
                                          (kc + 1) * 256 + sv[i] * 8);
        }
        const __bf16* sAb = sA[kc & 1];
        const __bf16* wq0 = wp0 + kc * 8 * 512;
        const __bf16* wq1 = wp1 + kc * 8 * 512;
#pragma unroll
        for (int c = 0; c < 8; c++) {
            int us = ((c * 4 + q) ^ xk) * 8;
            bfx8 a0 = *(const bfx8*)(sAb + ar0 + us);
            bfx8 a1 = *(const bfx8*)(sAb + ar1 + us);
            bfx8 a2 = *(const bfx8*)(sAb + ar2 + us);
            bfx8 a3 = *(const bfx8*)(sAb + ar3 + us);
            bfx8 w0 = *(const bfx8*)(wq0 + c * 512);
            bfx8 w1 = *(const bfx8*)(wq1 + c * 512);
            acc[0][0] = MFMA(a0, w0, acc[0][0], 0, 0, 0);
            acc[0][1] = MFMA(a1, w0, acc[0][1], 0, 0, 0);
            acc[0][2] = MFMA(a2, w0, acc[0][2], 0, 0, 0);
            acc[0][3] = MFMA(a3, w0, acc[0][3], 0, 0, 0);
            acc[1][0] = MFMA(a0, w1, acc[1][0], 0, 0, 0);
            acc[1][1] = MFMA(a1, w1, acc[1][1], 0, 0, 0);
            acc[1][2] = MFMA(a2, w1, acc[1][2], 0, 0, 0);
            acc[1][3] = MFMA(a3, w1, acc[1][3], 0, 0, 0);
        }
        if (kc < 3) {
#pragma unroll
            for (int i = 0; i < 4; i++)
                *(uint4*)(&sA[(kc + 1) & 1][so[i]]) = regs[i];
            __syncthreads();
        }
    }

#pragma unroll
    for (int nn = 0; nn < 2; nn++) {
        const int col = n0 + (w * 2 + nn) * 16 + r15;
#pragma unroll
        for (int mf = 0; mf < 4; mf++) {
#pragma unroll
            for (int reg = 0; reg < 4; reg++) {
                int row = m0 + mf * 16 + q * 4 + reg;
                Cout[(size_t)row * 1024 + col] = (__bf16)acc[nn][mf][reg];
            }
        }
    }
}

// ---------------------------------------------------------------------------
// gru_step v5: grid (32 j, 16 m), 256 thr (4 waves). No A staging; all
// operands direct from global (L2-resident). LDS = sGi/sGh handoffs only.
// One barrier. Waves 0-1: gh (jsub=w); waves 2-3: gi (jsub=w&1).
// Decoder: gh-waves also run gi c36..39 into acc2 (local add, 36/36).
// Encoder: gh-waves c0..19; gi-waves gi(8) + gh c20..31 -> sGh (20/20).
// Encoder t=0 (hb_in==nullptr): gh skipped entirely (h0=0 -> gh=bias).
// ---------------------------------------------------------------------------
#define GRU6(ACC, Aa, Ab, W0p, W1p, W2p)                          \
    {                                                             \
        bfx8 a0 = *(const bfx8*)(Aa + c * 32);                    \
        bfx8 a1 = *(const bfx8*)(Ab + c * 32);                    \
        bfx8 w0 = *(const bfx8*)(W0p + c * 512);                  \
        bfx8 w1 = *(const bfx8*)(W1p + c * 512);                  \
        bfx8 w2 = *(const bfx8*)(W2p + c * 512);                  \
        ACC[0][0] = MFMA(a0, w0, ACC[0][0], 0, 0, 0);             \
        ACC[0][1] = MFMA(a1, w0, ACC[0][1], 0, 0, 0);             \
        ACC[1][0] = MFMA(a0, w1, ACC[1][0], 0, 0, 0);             \
        ACC[1][1] = MFMA(a1, w1, ACC[1][1], 0, 0, 0);             \
        ACC[2][0] = MFMA(a0, w2, ACC[2][0], 0, 0, 0);             \
        ACC[2][1] = MFMA(a1, w2, ACC[2][1], 0, 0, 0);             \
    }

__global__ __launch_bounds__(256, 2) void gru_step(
    const __bf16* __restrict__ hb_in, __bf16* __restrict__ hb_out,
    const __bf16* __restrict__ sW1, const float* __restrict__ b1,
    const __bf16* __restrict__ sW2, const float* __restrict__ b2,
    int nK2, const int* __restrict__ src_t, int enc_t)
{
    __shared__ __align__(16) float sGi[3072];   // 12 KB
    __shared__ __align__(16) float sGh[3072];   // 12 KB (encoder handoff)
    const int tid = threadIdx.x;
    const int w = tid >> 6, lane = tid & 63;
    const int r15 = lane & 15, q = lane >> 4;
    const int j0 = blockIdx.x * 32, m0 = blockIdx.y * 32;
    const int jsub = w & 1;
    const int has_h = (hb_in != nullptr);

    const size_t tb = (size_t)(blockIdx.x * 2 + jsub);
    f32x4 acc[3][2], acc2[3][2];
#pragma unroll
    for (int s = 0; s < 3; s++)
#pragma unroll
        for (int ms = 0; ms < 2; ms++) {
            acc[s][ms]  = (f32x4){0.f, 0.f, 0.f, 0.f};
            acc2[s][ms] = (f32x4){0.f, 0.f, 0.f, 0.f};
        }

    const __bf16* H0 = hb_in + (size_t)(m0 + r15) * 1024 + q * 8;
    const __bf16* H1 = H0 + 16 * 1024;

    if (w < 2) {
        // ---- gh waves ----
        const __bf16* xp0 = sW1 + (tb * 32) * 512 + lane * 8;
        const __bf16* xp1 = xp0 + (size_t)64 * 32 * 512;
        const __bf16* xp2 = xp0 + (size_t)128 * 32 * 512;
        if (src_t) {
            if (has_h) {
#pragma unroll 4
                for (int c = 0; c < 20; c++) GRU6(acc, H0, H1, xp0, xp1, xp2)
            }
        } else {
#pragma unroll 8
            for (int c = 0; c < 32; c++) GRU6(acc, H0, H1, xp0, xp1, xp2)
            // decoder gi tail c 36..39 -> acc2 (local; epilogue adds)
            const __bf16* wp0 = sW2 + (tb * 40) * 512 + lane * 8;
            const __bf16* wp1 = wp0 + (size_t)64 * 40 * 512;
            const __bf16* wp2 = wp0 + (size_t)128 * 40 * 512;
            const __bf16* A0 = g_Adec + (size_t)(m0 + r15) * 1280 + q * 8;
            const __bf16* A1 = A0 + 16 * 1280;
#pragma unroll
            for (int c = 36; c < 40; c++) GRU6(acc2, A0, A1, wp0, wp1, wp2)
        }
    } else {
        // ---- gi waves ----
        if (src_t) {  // encoder: emb direct-gather, K=256 (8 frags)
            int s0 = src_t[m0 + r15];      s0 = (s0 < 0) ? 0 : (s0 > 63 ? 63 : s0);
            int s1 = src_t[m0 + 16 + r15]; s1 = (s1 < 0) ? 0 : (s1 > 63 ? 63 : s1);
            const __bf16* A0 = g_embs + s0 * 256 + q * 8;
            const __bf16* A1 = g_embs + s1 * 256 + q * 8;
            const __bf16* wp0 = sW2 + (tb * 8) * 512 + lane * 8;
            const __bf16* wp1 = wp0 + (size_t)64 * 8 * 512;
            const __bf16* wp2 = wp0 + (size_t)128 * 8 * 512;
#pragma unroll
            for (int c = 0; c < 8; c++) GRU6(acc, A0, A1, wp0, wp1, wp2)
            if (has_h) {
                // encoder gh tail c 20..31 -> acc2 -> sGh handoff
                const __bf16* xp0 = sW1 + (tb * 32) * 512 + lane * 8;
                const __bf16* xp1 = xp0 + (size_t)64 * 32 * 512;
                const __bf16* xp2 = xp0 + (size_t)128 * 32 * 512;
#pragma unroll 4
                for (int c = 20; c < 32; c++) GRU6(acc2, H0, H1, xp0, xp1, xp2)
#pragma unroll
                for (int s = 0; s < 3; s++)
#pragma unroll
                    for (int ms = 0; ms < 2; ms++)
#pragma unroll
                        for (int reg = 0; reg < 4; reg++)
                            sGh[((s * 2 + jsub) * 32 + ms * 16 + q * 4 + reg) * 16 + r15] =
                                acc2[s][ms][reg];
            }
        } else {      // decoder: Adec direct, c 0..35
            const __bf16* A0 = g_Adec + (size_t)(m0 + r15) * 1280 + q * 8;
            const __bf16* A1 = A0 + 16 * 1280;
            const __bf16* wp0 = sW2 + (tb * 40) * 512 + lane * 8;
            const __bf16* wp1 = wp0 + (size_t)64 * 40 * 512;
            const __bf16* wp2 = wp0 + (size_t)128 * 40 * 512;
#pragma unroll 4
            for (int c = 0; c < 36; c++) GRU6(acc, A0, A1, wp0, wp1, wp2)
        }
        // gi handoff
#pragma unroll
        for (int s = 0; s < 3; s++)
#pragma unroll
            for (int ms = 0; ms < 2; ms++)
#pragma unroll
                for (int reg = 0; reg < 4; reg++)
                    sGi[((s * 2 + jsub) * 32 + ms * 16 + q * 4 + reg) * 16 + r15] =
                        acc[s][ms][reg];
    }
    __syncthreads();
    if (w < 2) {
        const int jj = j0 + jsub * 16 + r15;
        const float bb1[3] = {b1[jj], b1[1024 + jj], b1[2048 + jj]};
        const float bb2[3] = {b2[jj], b2[1024 + jj], b2[2048 + jj]};
#pragma unroll
        for (int ms = 0; ms < 2; ms++) {
#pragma unroll
            for (int reg = 0; reg < 4; reg++) {
                int bl = ms * 16 + q * 4 + reg;
                int b_ = m0 + bl;
                float gh0 = acc[0][ms][reg] + bb1[0];
                float gh1 = acc[1][ms][reg] + bb1[1];
                float gh2 = acc[2][ms][reg] + bb1[2];
                float gi0 = sGi[((0 * 2 + jsub) * 32 + bl) * 16 + r15] + bb2[0];
                float gi1 = sGi[((1 * 2 + jsub) * 32 + bl) * 16 + r15] + bb2[1];
                float gi2 = sGi[((2 * 2 + jsub) * 32 + bl) * 16 + r15] + bb2[2];
                if (src_t) {
                    if (has_h) {
                        gh0 += sGh[((0 * 2 + jsub) * 32 + bl) * 16 + r15];
                        gh1 += sGh[((1 * 2 + jsub) * 32 + bl) * 16 + r15];
                        gh2 += sGh[((2 * 2 + jsub) * 32 + bl) * 16 + r15];
                    }
                } else {
                    gi0 += acc2[0][ms][reg];
                    gi1 += acc2[1][ms][reg];
                    gi2 += acc2[2][ms][reg];
                }
                float r = 1.f / (1.f + __expf(-(gi0 + gh0)));
                float z = 1.f / (1.f + __expf(-(gi1 + gh1)));
                float n = fast_tanh(gi2 + r * gh2);
                size_t off = (size_t)b_ * 1024 + jj;
                float hv = (1.f - z) * n + z * g_h[off];
                g_h[off] = hv;
                hb_out[off] = (__bf16)hv;
                if (enc_t >= 0)
                    g_enc_ops[(size_t)enc_t * 524288 + off] = (__bf16)hv;
            }
        }
    }
}

// ---------------------------------------------------------------------------
// k_hl v2: [hpart | logits] from h (bf16), de-staged: A read direct from
// global (L2-resident), 0 LDS, 0 barriers. grid (18, 16). bx<16: hpart
// col-tile; bx 16..17: logits (guard 70) -> out row lrow (skip if lrow<0).
// ---------------------------------------------------------------------------
__global__ __launch_bounds__(256) void k_hl(
    const __bf16* __restrict__ src, const float* __restrict__ battn,
    const float* __restrict__ bout, int lrow, float* __restrict__ outp)
{
    const int tid = threadIdx.x;
    const int w = tid >> 6, lane = tid & 63;
    const int r15 = lane & 15, q = lane >> 4;
    const int bx = blockIdx.x, m0 = blockIdx.y * 32;

    const __bf16* sW;
    int n;
    if (bx < 16) {
        sW = g_sWattnA;
        n = bx * 64 + w * 16 + r15;
    } else {
        if (lrow < 0) return;
        sW = g_sWout;
        n = (bx - 16) * 64 + w * 16 + r15;
    }
    const size_t tb = (size_t)((bx < 16 ? bx : bx - 16) * 4 + w);
    const __bf16* wp = sW + (tb * 32) * 512 + lane * 8;
    const __bf16* H0 = src + (size_t)(m0 + r15) * 1024 + q * 8;
    const __bf16* H1 = H0 + 16 * 1024;

    f32x4 acc[2];
    acc[0] = (f32x4){0.f, 0.f, 0.f, 0.f};
    acc[1] = (f32x4){0.f, 0.f, 0.f, 0.f};
#pragma unroll 8
    for (int c = 0; c < 32; c++) {
        bfx8 a0 = *(const bfx8*)(H0 + c * 32);
        bfx8 a1 = *(const bfx8*)(H1 + c * 32);
        bfx8 wv = *(const bfx8*)(wp + c * 512);
        acc[0] = MFMA(a0, wv, acc[0], 0, 0, 0);
        acc[1] = MFMA(a1, wv, acc[1], 0, 0, 0);
    }

    if (bx < 16) {
        float bv = battn[n];
#pragma unroll
        for (int ms = 0; ms < 2; ms++)
#pragma unroll
            for (int reg = 0; reg < 4; reg++)
                g_hpart[(size_t)(m0 + ms * 16 + q * 4 + reg) * 1024 + n] =
                    acc[ms][reg] + bv;
    } else if (n < 70) {
        float bv = bout[n];
#pragma unroll
        for (int ms = 0; ms < 2; ms++)
#pragma unroll
            for (int reg = 0; reg < 4; reg++)
                outp[(size_t)lrow * 35840 +
                     (size_t)(m0 + ms * 16 + q * 4 + reg) * 70 + n] =
                    acc[ms][reg] + bv;
    }
}

// ---------------------------------------------------------------------------
// Attention step: x-select + embed + scores + softmax + alpha out + ctx.
// One block per batch b.
// ---------------------------------------------------------------------------
__global__ __launch_bounds__(256) void k_attn(
    int j, const int* __restrict__ target, const int* __restrict__ tf,
    const float* __restrict__ v_attn, float* __restrict__ out)
{
    const int b = blockIdx.x, tid = threadIdx.x;
    const int lane = tid & 63, wave = tid >> 6;
    __shared__ float sc[32], sal[32];
    __shared__ int sx;
    if (wave == 0) {
        int xv;
        if (j == 0) xv = target[b];
        else if (*tf) xv = target[j * 512 + b];
        else {
            const float* row = out + (size_t)j * 35840 + b * 70;
            float bv = row[lane]; int bi = lane;
            if (lane < 6) {
                float v2 = row[lane + 64];
                if (v2 > bv) { bv = v2; bi = lane + 64; }
            }
#pragma unroll
            for (int off = 32; off; off >>= 1) {
                float ov = __shfl_down(bv, off);
                int   oi = __shfl_down(bi, off);
                if (ov > bv || (ov == bv && oi < bi)) { bv = ov; bi = oi; }
            }
            xv = bi;
        }
        if (lane == 0) sx = (xv < 0) ? 0 : (xv > 69 ? 69 : xv);
    }
    float hpv[16], vsv[16];
    {
        const float* hp = g_hpart + (size_t)b * 1024;
#pragma unroll
        for (int u = 0; u < 8; u++) {
            hpv[u]     = hp[lane * 8 + u];
            hpv[8 + u] = hp[512 + lane * 8 + u];
            vsv[u]     = v_attn[lane * 8 + u];
            vsv[8 + u] = v_attn[512 + lane * 8 + u];
        }
    }
    __syncthreads();
    g_Adec[(size_t)b * 1280 + 1024 + tid] = g_embt[sx * 256 + tid];
    for (int s = wave * 8; s < wave * 8 + 8; s++) {
        const __bf16* ep = g_enc_part + ((size_t)s * 512 + b) * 1024;
        bfx8 e0 = *(const bfx8*)(ep + lane * 8);
        bfx8 e1 = *(const bfx8*)(ep + 512 + lane * 8);
        float part = 0.f;
#pragma unroll
        for (int u = 0; u < 8; u++) {
            part += vsv[u]     * fast_tanh((float)e0[u] + hpv[u]);
            part += vsv[8 + u] * fast_tanh((float)e1[u] + hpv[8 + u]);
        }
#pragma unroll
        for (int off = 32; off; off >>= 1) part += __shfl_down(part, off);
        if (lane == 0) sc[s] = part;
    }
    __syncthreads();
    float mx = sc[0];
#pragma unroll
    for (int s = 1; s < 32; s++) mx = fmaxf(mx, sc[s]);
    float den = 0.f;
#pragma unroll
    for (int s = 0; s < 32; s++) den += __expf(sc[s] - mx);
    float rden = 1.f / den;
    if (tid < 32) {
        float al = __expf(sc[tid] - mx) * rden;
        sal[tid] = al;
        out[1146880 + (size_t)j * 16384 + b * 32 + tid] = al;
    }
    __syncthreads();
    float c0 = 0, c1 = 0, c2 = 0, c3 = 0;
    const __bf16* eo = g_enc_ops + (size_t)b * 1024 + tid * 4;
#pragma unroll 4
    for (int s = 0; s < 32; s++) {
        bfx4 e = *(const bfx4*)(eo + (size_t)s * 524288);
        float al = sal[s];
        c0 += al * (float)e[0]; c1 += al * (float)e[1];
        c2 += al * (float)e[2]; c3 += al * (float)e[3];
    }
    bfx4 o = {(__bf16)c0, (__bf16)c1, (__bf16)c2, (__bf16)c3};
    *(bfx4*)(&g_Adec[(size_t)b * 1280 + tid * 4]) = o;
}

// ---------------------------------------------------------------------------
extern "C" void kernel_launch(void* const* d_in, const int* in_sizes, int n_in,
                              void* d_out, int out_size, void* d_ws, size_t ws_size,
                              hipStream_t stream)
{
    const int*   source   = (const int*)d_in[0];
    const int*   target   = (const int*)d_in[1];
    const int*   tf       = (const int*)d_in[2];
    const float* emb_src  = (const float*)d_in[3];
    const float* W_ih_enc = (const float*)d_in[4];
    const float* W_hh_enc = (const float*)d_in[5];
    const float* b_ih_enc = (const float*)d_in[6];
    const float* b_hh_enc = (const float*)d_in[7];
    const float* emb_tgt  = (const float*)d_in[8];
    const float* W_attn   = (const float*)d_in[9];
    const float* b_attn   = (const float*)d_in[10];
    const float* v_attn   = (const float*)d_in[11];
    const float* W_ih_dec = (const float*)d_in[12];
    const float* W_hh_dec = (const float*)d_in[13];
    const float* b_ih_dec = (const float*)d_in[14];
    const float* b_hh_dec = (const float*)d_in[15];
    const float* W_out    = (const float*)d_in[16];
    const float* b_out    = (const float*)d_in[17];
    float* out = (float*)d_out;

    void *p_hb, *p_sWhhe, *p_sWihe, *p_sWhhd, *p_sWihd, *p_sWattnA, *p_sWattnB,
         *p_sWout, *p_embs, *p_embt, *p_enc_ops, *p_enc_part;
    hipGetSymbolAddress(&p_hb,       HIP_SYMBOL(g_hb));
    hipGetSymbolAddress(&p_sWhhe,    HIP_SYMBOL(g_sWhhe));
    hipGetSymbolAddress(&p_sWihe,    HIP_SYMBOL(g_sWihe));
    hipGetSymbolAddress(&p_sWhhd,    HIP_SYMBOL(g_sWhhd));
    hipGetSymbolAddress(&p_sWihd,    HIP_SYMBOL(g_sWihd));
    hipGetSymbolAddress(&p_sWattnA,  HIP_SYMBOL(g_sWattnA));
    hipGetSymbolAddress(&p_sWattnB,  HIP_SYMBOL(g_sWattnB));
    hipGetSymbolAddress(&p_sWout,    HIP_SYMBOL(g_sWout));
    hipGetSymbolAddress(&p_embs,     HIP_SYMBOL(g_embs));
    hipGetSymbolAddress(&p_embt,     HIP_SYMBOL(g_embt));
    hipGetSymbolAddress(&p_enc_ops,  HIP_SYMBOL(g_enc_ops));
    hipGetSymbolAddress(&p_enc_part, HIP_SYMBOL(g_enc_part));
    __bf16* hb0 = (__bf16*)p_hb;
    __bf16* hb1 = hb0 + 512 * 1024;

    // ---- one-time setup ----
    k_cvt<<<16, 256, 0, stream>>>(emb_src, (__bf16*)p_embs, 64 * 256 / 4);
    k_cvt<<<18, 256, 0, stream>>>(emb_tgt, (__bf16*)p_embt, 70 * 256 / 4);
    swz_rm<<<1536, 256, 0, stream>>>(W_hh_enc, (__bf16*)p_sWhhe, 32, 393216);
    swz_rm<<<384,  256, 0, stream>>>(W_ih_enc, (__bf16*)p_sWihe, 8,  98304);
    swz_rm<<<1536, 256, 0, stream>>>(W_hh_dec, (__bf16*)p_sWhhd, 32, 393216);
    swz_rm<<<1920, 256, 0, stream>>>(W_ih_dec, (__bf16*)p_sWihd, 40, 491520);
    swz_cm<<<512,  256, 0, stream>>>(W_attn, (__bf16*)p_sWattnA, 32, 1024, 1024, 131072);
    swz_cm<<<512,  256, 0, stream>>>(W_attn + (size_t)1024 * 1024,
                                     (__bf16*)p_sWattnB, 32, 1024, 1024, 131072);
    swz_cm<<<64,   256, 0, stream>>>(W_out,  (__bf16*)p_sWout,   32, 70,   70,   16384);
    k_init<<<2048, 256, 0, stream>>>(out);

    // -------- Encoder: 32 steps (t=0: h0==0 -> gh skipped via nullptr) ----
    for (int t = 0; t < 32; t++) {
        __bf16* hin  = (t == 0) ? nullptr : ((t & 1) ? hb1 : hb0);
        __bf16* hout = (t & 1) ? hb0 : hb1;
        gru_step<<<dim3(32, 16), 256, 0, stream>>>(
            hin, hout, (__bf16*)p_sWhhe, b_hh_enc,
            (__bf16*)p_sWihe, b_ih_enc, 8, source + t * 512, t);
    }
    // h_enc lands in hb0

    // enc_part = enc_ops @ W_attn[H:2H]^T  (frag-major weights, no bias)
    k_encpart<<<dim3(1024), 512, 0, stream>>>(
        (__bf16*)p_enc_ops, (__bf16*)p_sWattnB, (__bf16*)p_enc_part);

    // hpart for step 0
    k_hl<<<dim3(18, 16), 256, 0, stream>>>(hb0, b_attn, b_out, -1, out);

    // -------- Decoder: 31 steps --------
    for (int j = 0; j < 31; j++) {
        __bf16* hin  = (j & 1) ? hb1 : hb0;
        __bf16* hout = (j & 1) ? hb0 : hb1;
        k_attn<<<512, 256, 0, stream>>>(j, target, tf, v_attn, out);
        gru_step<<<dim3(32, 16), 256, 0, stream>>>(
            hin, hout, (__bf16*)p_sWhhd, b_hh_dec,
            (__bf16*)p_sWihd, b_ih_dec, 40, nullptr, -1);
        k_hl<<<dim3(18, 16), 256, 0, stream>>>(hout, b_attn, b_out, j + 1, out);
    }
}

// Round 6
// 2289.172 us; speedup vs baseline: 1.2458x; 1.2458x over previous
//
#include <hip/hip_runtime.h>
#include <hip/hip_bf16.h>

typedef __bf16 bfx8 __attribute__((ext_vector_type(8)));
typedef __bf16 bfx4 __attribute__((ext_vector_type(4)));
typedef float f32x4 __attribute__((ext_vector_type(4)));

#define MFMA __builtin_amdgcn_mfma_f32_16x16x32_bf16

// Dims: S=32 T=32 B=512 H=1024 E=256 A=1024 VS=64 VT=70 START=1
// R4 structure (best measured: 2275us). Separate launches (coop grid.sync
// measured ~35us/sync -- never again). Weights pre-swizzled fragment-major.
// A-operands LDS-staged (R5 proved de-staging costs ~+6us/dispatch: direct
// global fragment reads are 16B-scattered L2-latency-bound).
// gru_step v4: grid (32 j, 16 m) x 256 thr, 76KB LDS -> 2 blocks/CU.
// Waves 0-1 gh (LDS-staged A1), 2-3 gi (direct A2). Decoder balanced 36/36
// via local acc2 tail; encoder 20/12+8 via sGh handoff.
// k_encpart: XCD-swizzled; NEW: C-tile staged in LDS -> coalesced 512B-row
// writes (was 2B-scatter; WRITE_SIZE 37MB, HBM-bound at 1.7TB/s).

__device__ __attribute__((aligned(256))) float  g_h[512 * 1024];
__device__ __attribute__((aligned(256))) float  g_hpart[512 * 1024];
__device__ __attribute__((aligned(256))) __bf16 g_hb[2][512 * 1024];
__device__ __attribute__((aligned(256))) __bf16 g_Adec[512 * 1280];
__device__ __attribute__((aligned(256))) __bf16 g_enc_ops[(size_t)32 * 512 * 1024];
__device__ __attribute__((aligned(256))) __bf16 g_enc_part[(size_t)32 * 512 * 1024];
__device__ __attribute__((aligned(256))) __bf16 g_sWhhe[(size_t)3072 * 1024];   // fragment-major
__device__ __attribute__((aligned(256))) __bf16 g_sWihe[(size_t)3072 * 256];
__device__ __attribute__((aligned(256))) __bf16 g_sWhhd[(size_t)3072 * 1024];
__device__ __attribute__((aligned(256))) __bf16 g_sWihd[(size_t)3072 * 1280];
__device__ __attribute__((aligned(256))) __bf16 g_sWattnA[(size_t)1024 * 1024];
__device__ __attribute__((aligned(256))) __bf16 g_sWattnB[(size_t)1024 * 1024]; // W_attn[H:2H] frag-major
__device__ __attribute__((aligned(256))) __bf16 g_sWout[(size_t)128 * 1024];
__device__ __attribute__((aligned(256))) __bf16 g_embs[64 * 256];
__device__ __attribute__((aligned(256))) __bf16 g_embt[70 * 256];

__device__ __forceinline__ float fast_tanh(float x) {
    float cx = fminf(fmaxf(x, -15.f), 15.f);
    float e = __expf(-2.f * cx);
    return (1.f - e) / (1.f + e);
}

// ---------------------------------------------------------------------------
__global__ void k_cvt(const float* __restrict__ src, __bf16* __restrict__ dst,
                      int n4)
{
    int i = blockIdx.x * 256 + threadIdx.x;
    if (i >= n4) return;
    float4 v = ((const float4*)src)[i];
    __bf16 o[4] = {(__bf16)v.x, (__bf16)v.y, (__bf16)v.z, (__bf16)v.w};
    *(ushort2*)(dst + 4 * i) = *(ushort2*)o;
    *(ushort2*)(dst + 4 * i + 2) = *(ushort2*)(o + 2);
}

// Row-major f32 W[R][K] -> fragment-major bf16.
__global__ void swz_rm(const float* __restrict__ W, __bf16* __restrict__ out,
                       int nK, int total)
{
    int gid = blockIdx.x * 256 + threadIdx.x;
    if (gid >= total) return;
    int F = gid >> 6, L = gid & 63;
    int t = F / nK, c = F - t * nK;
    int K = nK * 32;
    const float* s = W + (size_t)(t * 16 + (L & 15)) * K + c * 32 + (L >> 4) * 8;
    __bf16 o[8];
#pragma unroll
    for (int u = 0; u < 8; u++) o[u] = (__bf16)s[u];
    *(uint4*)(out + (size_t)gid * 8) = *(uint4*)o;
}

// Column-gather: logical W'[n][k] = W[k*ldsrc + n]; n>=nguard -> 0.
__global__ void swz_cm(const float* __restrict__ W, __bf16* __restrict__ out,
                       int nK, int ldsrc, int nguard, int total)
{
    int gid = blockIdx.x * 256 + threadIdx.x;
    if (gid >= total) return;
    int F = gid >> 6, L = gid & 63;
    int t = F / nK, c = F - t * nK;
    int n = t * 16 + (L & 15);
    int k = c * 32 + (L >> 4) * 8;
    __bf16 o[8];
#pragma unroll
    for (int u = 0; u < 8; u++)
        o[u] = (n < nguard) ? (__bf16)W[(size_t)(k + u) * ldsrc + n] : (__bf16)0.f;
    *(uint4*)(out + (size_t)gid * 8) = *(uint4*)o;
}

__global__ void k_init(float* __restrict__ out)
{
    int idx = blockIdx.x * 256 + threadIdx.x;
    if (idx < 512 * 1024) { g_h[idx] = 0.f; g_hb[0][idx] = (__bf16)0.f; }
    if (idx < 512 * 70) out[idx] = (idx % 70 == 1) ? 1.f : 0.f;
}

// ---------------------------------------------------------------------------
// k_encpart: enc_part = enc_ops(16384x1024) @ W_attn[H:2H]^T (frag-major).
// 1024 blocks x 512 thr, XCD-swizzled: XCD r owns m-tiles [r*32, r*32+32)
// with all 4 n-blocks co-located -> A-tile HBM-fetched once per XCD.
// A double-buffered in 32KB K-chunks (2 blocks/CU). C-tile staged in LDS
// (reuse sA[0], dead after kc=2 barrier) -> coalesced 512B-row writes.
// ---------------------------------------------------------------------------
__global__ __launch_bounds__(512, 4) void k_encpart(
    const __bf16* __restrict__ Amat, const __bf16* __restrict__ sW,
    __bf16* __restrict__ Cout)
{
    __shared__ __bf16 sA[2][64 * 256];   // 2 x 32 KB
    const int tid = threadIdx.x;
    const int w = tid >> 6, lane = tid & 63;
    const int r15 = lane & 15, q = lane >> 4;
    const int sw = (blockIdx.x & 7) * 128 + (blockIdx.x >> 3);
    const int nx = sw & 3;
    const int n0 = nx * 256, m0 = (sw >> 2) * 64;

    int sr[4], sv[4], so[4];
#pragma unroll
    for (int i = 0; i < 4; i++) {
        int lin = tid + i * 512;
        sr[i] = lin >> 5;
        sv[i] = lin & 31;
        so[i] = (sr[i] * 32 + (sv[i] ^ (sr[i] & 7))) * 8;
    }

    uint4 regs[4];
#pragma unroll
    for (int i = 0; i < 4; i++)
        regs[i] = *(const uint4*)(Amat + (size_t)(m0 + sr[i]) * 1024 + sv[i] * 8);
#pragma unroll
    for (int i = 0; i < 4; i++)
        *(uint4*)(&sA[0][so[i]]) = regs[i];
    __syncthreads();

    const int xk = r15 & 7;
    f32x4 acc[2][4];
#pragma unroll
    for (int nn = 0; nn < 2; nn++)
#pragma unroll
        for (int mf = 0; mf < 4; mf++) acc[nn][mf] = (f32x4){0.f, 0.f, 0.f, 0.f};

    const __bf16* wp0 = sW + ((size_t)(nx * 16 + w * 2) * 32) * 512 + lane * 8;
    const __bf16* wp1 = wp0 + 32 * 512;
    const int ar0 = r15 * 256;
    const int ar1 = (16 + r15) * 256;
    const int ar2 = (32 + r15) * 256;
    const int ar3 = (48 + r15) * 256;

    for (int kc = 0; kc < 4; kc++) {
        if (kc < 3) {
#pragma unroll
            for (int i = 0; i < 4; i++)
                regs[i] = *(const uint4*)(Amat + (size_t)(m0 + sr[i]) * 1024 +
                                          (kc + 1) * 256 + sv[i] * 8);
        }
        const __bf16* sAb = sA[kc & 1];
        const __bf16* wq0 = wp0 + kc * 8 * 512;
        const __bf16* wq1 = wp1 + kc * 8 * 512;
#pragma unroll
        for (int c = 0; c < 8; c++) {
            int us = ((c * 4 + q) ^ xk) * 8;
            bfx8 a0 = *(const bfx8*)(sAb + ar0 + us);
            bfx8 a1 = *(const bfx8*)(sAb + ar1 + us);
            bfx8 a2 = *(const bfx8*)(sAb + ar2 + us);
            bfx8 a3 = *(const bfx8*)(sAb + ar3 + us);
            bfx8 w0 = *(const bfx8*)(wq0 + c * 512);
            bfx8 w1 = *(const bfx8*)(wq1 + c * 512);
            acc[0][0] = MFMA(a0, w0, acc[0][0], 0, 0, 0);
            acc[0][1] = MFMA(a1, w0, acc[0][1], 0, 0, 0);
            acc[0][2] = MFMA(a2, w0, acc[0][2], 0, 0, 0);
            acc[0][3] = MFMA(a3, w0, acc[0][3], 0, 0, 0);
            acc[1][0] = MFMA(a0, w1, acc[1][0], 0, 0, 0);
            acc[1][1] = MFMA(a1, w1, acc[1][1], 0, 0, 0);
            acc[1][2] = MFMA(a2, w1, acc[1][2], 0, 0, 0);
            acc[1][3] = MFMA(a3, w1, acc[1][3], 0, 0, 0);
        }
        if (kc < 3) {
#pragma unroll
            for (int i = 0; i < 4; i++)
                *(uint4*)(&sA[(kc + 1) & 1][so[i]]) = regs[i];
            __syncthreads();
        }
    }

    // ---- coalesced C-write: stage C-tile in sA[0] (dead: last read was
    // kc=2, all waves passed the kc=2-end barrier; kc=3 reads only sA[1]),
    // then stream 64 rows x 512B contiguous. ----
    __bf16* sC = sA[0];
#pragma unroll
    for (int nn = 0; nn < 2; nn++) {
        const int cl = (w * 2 + nn) * 16 + r15;
#pragma unroll
        for (int mf = 0; mf < 4; mf++) {
#pragma unroll
            for (int reg = 0; reg < 4; reg++) {
                int row = mf * 16 + q * 4 + reg;
                sC[row * 256 + cl] = (__bf16)acc[nn][mf][reg];
            }
        }
    }
    __syncthreads();
#pragma unroll
    for (int i = 0; i < 4; i++) {
        int lin = tid + i * 512;
        int row = lin >> 5, unit = lin & 31;
        *(uint4*)(Cout + (size_t)(m0 + row) * 1024 + n0 + unit * 8) =
            *(const uint4*)(sC + row * 256 + unit * 8);
    }
}

// ---------------------------------------------------------------------------
// gru_step v4: grid (32 j, 16 m), 256 thr (4 waves), 76KB LDS, 2 blocks/CU.
// Waves 0-1: gh (jsub=w). Waves 2-3: gi (jsub=w&1). A2 read direct from
// global. Decoder: gh-waves take gi c36..39 into acc2 (added locally in
// epilogue). Encoder: gh-waves c0..19; gi-waves gi(8) + gh c20..31 -> sGh.
// LDS: sA1 [0,64K) (sGi overlaps [0,12K) post-barrier); sGh [64K,76K).
// ---------------------------------------------------------------------------
#define GH_BODY(ACC)                                              \
    {                                                             \
        int us = ((c * 4 + q) ^ xk) * 8;                          \
        bfx8 a0 = *(const bfx8*)(sA1 + br0 + us);                 \
        bfx8 a1 = *(const bfx8*)(sA1 + br1 + us);                 \
        bfx8 w0 = *(const bfx8*)(xp0 + c * 512);                  \
        bfx8 w1 = *(const bfx8*)(xp1 + c * 512);                  \
        bfx8 w2 = *(const bfx8*)(xp2 + c * 512);                  \
        ACC[0][0] = MFMA(a0, w0, ACC[0][0], 0, 0, 0);             \
        ACC[0][1] = MFMA(a1, w0, ACC[0][1], 0, 0, 0);             \
        ACC[1][0] = MFMA(a0, w1, ACC[1][0], 0, 0, 0);             \
        ACC[1][1] = MFMA(a1, w1, ACC[1][1], 0, 0, 0);             \
        ACC[2][0] = MFMA(a0, w2, ACC[2][0], 0, 0, 0);             \
        ACC[2][1] = MFMA(a1, w2, ACC[2][1], 0, 0, 0);             \
    }

#define GI_BODY(ACC)                                              \
    {                                                             \
        bfx8 a0 = *(const bfx8*)(A0 + c * 32);                    \
        bfx8 a1 = *(const bfx8*)(A1 + c * 32);                    \
        bfx8 w0 = *(const bfx8*)(wp0 + c * 512);                  \
        bfx8 w1 = *(const bfx8*)(wp1 + c * 512);                  \
        bfx8 w2 = *(const bfx8*)(wp2 + c * 512);                  \
        ACC[0][0] = MFMA(a0, w0, ACC[0][0], 0, 0, 0);             \
        ACC[0][1] = MFMA(a1, w0, ACC[0][1], 0, 0, 0);             \
        ACC[1][0] = MFMA(a0, w1, ACC[1][0], 0, 0, 0);             \
        ACC[1][1] = MFMA(a1, w1, ACC[1][1], 0, 0, 0);             \
        ACC[2][0] = MFMA(a0, w2, ACC[2][0], 0, 0, 0);             \
        ACC[2][1] = MFMA(a1, w2, ACC[2][1], 0, 0, 0);             \
    }

__global__ __launch_bounds__(256, 2) void gru_step(
    const __bf16* __restrict__ hb_in, __bf16* __restrict__ hb_out,
    const __bf16* __restrict__ sW1, const float* __restrict__ b1,
    const __bf16* __restrict__ sW2, const float* __restrict__ b2,
    int nK2, const int* __restrict__ src_t, int enc_t)
{
    __shared__ __align__(16) unsigned char smem[77824];
    __bf16* sA1 = (__bf16*)smem;            // 64 KB
    float*  sGi = (float*)smem;             // 12 KB (post-barrier overlap)
    float*  sGh = (float*)(smem + 65536);   // 12 KB (encoder handoff)
    const int tid = threadIdx.x;
    const int w = tid >> 6, lane = tid & 63;
    const int r15 = lane & 15, q = lane >> 4;
    const int j0 = blockIdx.x * 32, m0 = blockIdx.y * 32;
    const int jsub = w & 1;

    // ---- stage A1: 32 rows x 128 16B-units, xor-swizzled ----
#pragma unroll
    for (int i = 0; i < 16; i++) {
        int lin = tid + i * 256;
        int r = lin >> 7, U = lin & 127;
        uint4 v = *(const uint4*)(hb_in + (size_t)(m0 + r) * 1024 + U * 8);
        *(uint4*)(sA1 + (r * 128 + (U ^ (r & 7))) * 8) = v;
    }
    __syncthreads();

    const size_t tb = (size_t)(blockIdx.x * 2 + jsub);
    const int xk = r15 & 7;
    f32x4 acc[3][2], acc2[3][2];
#pragma unroll
    for (int s = 0; s < 3; s++)
#pragma unroll
        for (int ms = 0; ms < 2; ms++) {
            acc[s][ms]  = (f32x4){0.f, 0.f, 0.f, 0.f};
            acc2[s][ms] = (f32x4){0.f, 0.f, 0.f, 0.f};
        }

    if (w < 2) {
        // ---- gh waves ----
        const __bf16* xp0 = sW1 + (tb * 32) * 512 + lane * 8;
        const __bf16* xp1 = sW1 + ((tb + 64) * 32) * 512 + lane * 8;
        const __bf16* xp2 = sW1 + ((tb + 128) * 32) * 512 + lane * 8;
        const int br0 = r15 * 1024, br1 = (16 + r15) * 1024;
        if (src_t) {
#pragma unroll 4
            for (int c = 0; c < 20; c++) GH_BODY(acc)
        } else {
#pragma unroll 8
            for (int c = 0; c < 32; c++) GH_BODY(acc)
            // decoder gi tail c 36..39 -> acc2 (local; epilogue adds)
            const __bf16* wp0 = sW2 + (tb * 40) * 512 + lane * 8;
            const __bf16* wp1 = sW2 + ((tb + 64) * 40) * 512 + lane * 8;
            const __bf16* wp2 = sW2 + ((tb + 128) * 40) * 512 + lane * 8;
            const __bf16* A0 = g_Adec + (size_t)(m0 + r15) * 1280 + q * 8;
            const __bf16* A1 = A0 + 16 * 1280;
#pragma unroll
            for (int c = 36; c < 40; c++) GI_BODY(acc2)
        }
    } else {
        // ---- gi waves ----
        if (src_t) {  // encoder: emb direct-gather, K=256 (8 frags)
            int s0 = src_t[m0 + r15];      s0 = (s0 < 0) ? 0 : (s0 > 63 ? 63 : s0);
            int s1 = src_t[m0 + 16 + r15]; s1 = (s1 < 0) ? 0 : (s1 > 63 ? 63 : s1);
            const __bf16* A0 = g_embs + s0 * 256 + q * 8;
            const __bf16* A1 = g_embs + s1 * 256 + q * 8;
            const __bf16* wp0 = sW2 + (tb * 8) * 512 + lane * 8;
            const __bf16* wp1 = sW2 + ((tb + 64) * 8) * 512 + lane * 8;
            const __bf16* wp2 = sW2 + ((tb + 128) * 8) * 512 + lane * 8;
#pragma unroll
            for (int c = 0; c < 8; c++) GI_BODY(acc)
            // encoder gh tail c 20..31 -> acc2 -> sGh handoff
            const __bf16* xp0 = sW1 + (tb * 32) * 512 + lane * 8;
            const __bf16* xp1 = sW1 + ((tb + 64) * 32) * 512 + lane * 8;
            const __bf16* xp2 = sW1 + ((tb + 128) * 32) * 512 + lane * 8;
            const int br0 = r15 * 1024, br1 = (16 + r15) * 1024;
#pragma unroll 4
            for (int c = 20; c < 32; c++) GH_BODY(acc2)
            // sGh region disjoint from sA1 -> safe pre-barrier
#pragma unroll
            for (int s = 0; s < 3; s++)
#pragma unroll
                for (int ms = 0; ms < 2; ms++)
#pragma unroll
                    for (int reg = 0; reg < 4; reg++)
                        sGh[((s * 2 + jsub) * 32 + ms * 16 + q * 4 + reg) * 16 + r15] =
                            acc2[s][ms][reg];
        } else {      // decoder: Adec direct, c 0..35
            const __bf16* A0 = g_Adec + (size_t)(m0 + r15) * 1280 + q * 8;
            const __bf16* A1 = A0 + 16 * 1280;
            const __bf16* wp0 = sW2 + (tb * 40) * 512 + lane * 8;
            const __bf16* wp1 = sW2 + ((tb + 64) * 40) * 512 + lane * 8;
            const __bf16* wp2 = sW2 + ((tb + 128) * 40) * 512 + lane * 8;
#pragma unroll 4
            for (int c = 0; c < 36; c++) GI_BODY(acc)
        }
    }
    __syncthreads();   // gh K-loops done; sA1 dead -> sGi may overlap it
    if (w >= 2) {
#pragma unroll
        for (int s = 0; s < 3; s++)
#pragma unroll
            for (int ms = 0; ms < 2; ms++)
#pragma unroll
                for (int reg = 0; reg < 4; reg++)
                    sGi[((s * 2 + jsub) * 32 + ms * 16 + q * 4 + reg) * 16 + r15] =
                        acc[s][ms][reg];
    }
    __syncthreads();
    if (w < 2) {
        const int jj = j0 + jsub * 16 + r15;
        const float bb1[3] = {b1[jj], b1[1024 + jj], b1[2048 + jj]};
        const float bb2[3] = {b2[jj], b2[1024 + jj], b2[2048 + jj]};
#pragma unroll
        for (int ms = 0; ms < 2; ms++) {
#pragma unroll
            for (int reg = 0; reg < 4; reg++) {
                int bl = ms * 16 + q * 4 + reg;
                int b_ = m0 + bl;
                float gh0 = acc[0][ms][reg] + bb1[0];
                float gh1 = acc[1][ms][reg] + bb1[1];
                float gh2 = acc[2][ms][reg] + bb1[2];
                float gi0 = sGi[((0 * 2 + jsub) * 32 + bl) * 16 + r15] + bb2[0];
                float gi1 = sGi[((1 * 2 + jsub) * 32 + bl) * 16 + r15] + bb2[1];
                float gi2 = sGi[((2 * 2 + jsub) * 32 + bl) * 16 + r15] + bb2[2];
                if (src_t) {
                    gh0 += sGh[((0 * 2 + jsub) * 32 + bl) * 16 + r15];
                    gh1 += sGh[((1 * 2 + jsub) * 32 + bl) * 16 + r15];
                    gh2 += sGh[((2 * 2 + jsub) * 32 + bl) * 16 + r15];
                } else {
                    gi0 += acc2[0][ms][reg];
                    gi1 += acc2[1][ms][reg];
                    gi2 += acc2[2][ms][reg];
                }
                float r = 1.f / (1.f + __expf(-(gi0 + gh0)));
                float z = 1.f / (1.f + __expf(-(gi1 + gh1)));
                float n = fast_tanh(gi2 + r * gh2);
                size_t off = (size_t)b_ * 1024 + jj;
                float hv = (1.f - z) * n + z * g_h[off];
                g_h[off] = hv;
                hb_out[off] = (__bf16)hv;
                if (enc_t >= 0)
                    g_enc_ops[(size_t)enc_t * 524288 + off] = (__bf16)hv;
            }
        }
    }
}

// ---------------------------------------------------------------------------
// Fused [hpart | logits] from h (bf16). grid (18, 16). bx<16: hpart col-tile;
// bx 16..17: logits (guard 70) -> out row lrow (skipped if lrow<0).
// ---------------------------------------------------------------------------
__global__ __launch_bounds__(256) void k_hl(
    const __bf16* __restrict__ src, const float* __restrict__ battn,
    const float* __restrict__ bout, int lrow, float* __restrict__ outp)
{
    __shared__ __bf16 sA[32 * 1024];
    const int tid = threadIdx.x;
    const int w = tid >> 6, lane = tid & 63;
    const int r15 = lane & 15, q = lane >> 4;
    const int bx = blockIdx.x, m0 = blockIdx.y * 32;

#pragma unroll
    for (int i = 0; i < 16; i++) {
        int lin = tid + i * 256;
        int r = lin >> 7, U = lin & 127;
        uint4 v = *(const uint4*)(src + (size_t)(m0 + r) * 1024 + U * 8);
        *(uint4*)(sA + (r * 128 + (U ^ (r & 7))) * 8) = v;
    }
    __syncthreads();

    const __bf16* sW;
    int n;
    if (bx < 16) {
        sW = g_sWattnA;
        n = bx * 64 + w * 16 + r15;
    } else {
        if (lrow < 0) return;
        sW = g_sWout;
        n = (bx - 16) * 64 + w * 16 + r15;
    }
    const size_t tb = (size_t)((bx < 16 ? bx : bx - 16) * 4 + w);
    const __bf16* wp = sW + (tb * 32) * 512 + lane * 8;
    const int xk = r15 & 7;
    const int ar0 = r15 * 1024, ar1 = (16 + r15) * 1024;

    f32x4 acc[2];
    acc[0] = (f32x4){0.f, 0.f, 0.f, 0.f};
    acc[1] = (f32x4){0.f, 0.f, 0.f, 0.f};
#pragma unroll 8
    for (int c = 0; c < 32; c++) {
        int us = ((c * 4 + q) ^ xk) * 8;
        bfx8 a0 = *(const bfx8*)(sA + ar0 + us);
        bfx8 a1 = *(const bfx8*)(sA + ar1 + us);
        bfx8 wv = *(const bfx8*)(wp + c * 512);
        acc[0] = MFMA(a0, wv, acc[0], 0, 0, 0);
        acc[1] = MFMA(a1, wv, acc[1], 0, 0, 0);
    }

    if (bx < 16) {
        float bv = battn[n];
#pragma unroll
        for (int ms = 0; ms < 2; ms++)
#pragma unroll
            for (int reg = 0; reg < 4; reg++)
                g_hpart[(size_t)(m0 + ms * 16 + q * 4 + reg) * 1024 + n] =
                    acc[ms][reg] + bv;
    } else if (n < 70) {
        float bv = bout[n];
#pragma unroll
        for (int ms = 0; ms < 2; ms++)
#pragma unroll
            for (int reg = 0; reg < 4; reg++)
                outp[(size_t)lrow * 35840 +
                     (size_t)(m0 + ms * 16 + q * 4 + reg) * 70 + n] =
                    acc[ms][reg] + bv;
    }
}

// ---------------------------------------------------------------------------
// Attention step: x-select + embed + scores + softmax + alpha out + ctx.
// One block per batch b.
// ---------------------------------------------------------------------------
__global__ __launch_bounds__(256) void k_attn(
    int j, const int* __restrict__ target, const int* __restrict__ tf,
    const float* __restrict__ v_attn, float* __restrict__ out)
{
    const int b = blockIdx.x, tid = threadIdx.x;
    const int lane = tid & 63, wave = tid >> 6;
    __shared__ float sc[32], sal[32];
    __shared__ int sx;
    if (wave == 0) {
        int xv;
        if (j == 0) xv = target[b];
        else if (*tf) xv = target[j * 512 + b];
        else {
            const float* row = out + (size_t)j * 35840 + b * 70;
            float bv = row[lane]; int bi = lane;
            if (lane < 6) {
                float v2 = row[lane + 64];
                if (v2 > bv) { bv = v2; bi = lane + 64; }
            }
#pragma unroll
            for (int off = 32; off; off >>= 1) {
                float ov = __shfl_down(bv, off);
                int   oi = __shfl_down(bi, off);
                if (ov > bv || (ov == bv && oi < bi)) { bv = ov; bi = oi; }
            }
            xv = bi;
        }
        if (lane == 0) sx = (xv < 0) ? 0 : (xv > 69 ? 69 : xv);
    }
    float hpv[16], vsv[16];
    {
        const float* hp = g_hpart + (size_t)b * 1024;
#pragma unroll
        for (int u = 0; u < 8; u++) {
            hpv[u]     = hp[lane * 8 + u];
            hpv[8 + u] = hp[512 + lane * 8 + u];
            vsv[u]     = v_attn[lane * 8 + u];
            vsv[8 + u] = v_attn[512 + lane * 8 + u];
        }
    }
    __syncthreads();
    g_Adec[(size_t)b * 1280 + 1024 + tid] = g_embt[sx * 256 + tid];
    for (int s = wave * 8; s < wave * 8 + 8; s++) {
        const __bf16* ep = g_enc_part + ((size_t)s * 512 + b) * 1024;
        bfx8 e0 = *(const bfx8*)(ep + lane * 8);
        bfx8 e1 = *(const bfx8*)(ep + 512 + lane * 8);
        float part = 0.f;
#pragma unroll
        for (int u = 0; u < 8; u++) {
            part += vsv[u]     * fast_tanh((float)e0[u] + hpv[u]);
            part += vsv[8 + u] * fast_tanh((float)e1[u] + hpv[8 + u]);
        }
#pragma unroll
        for (int off = 32; off; off >>= 1) part += __shfl_down(part, off);
        if (lane == 0) sc[s] = part;
    }
    __syncthreads();
    float mx = sc[0];
#pragma unroll
    for (int s = 1; s < 32; s++) mx = fmaxf(mx, sc[s]);
    float den = 0.f;
#pragma unroll
    for (int s = 0; s < 32; s++) den += __expf(sc[s] - mx);
    float rden = 1.f / den;
    if (tid < 32) {
        float al = __expf(sc[tid] - mx) * rden;
        sal[tid] = al;
        out[1146880 + (size_t)j * 16384 + b * 32 + tid] = al;
    }
    __syncthreads();
    float c0 = 0, c1 = 0, c2 = 0, c3 = 0;
    const __bf16* eo = g_enc_ops + (size_t)b * 1024 + tid * 4;
#pragma unroll 4
    for (int s = 0; s < 32; s++) {
        bfx4 e = *(const bfx4*)(eo + (size_t)s * 524288);
        float al = sal[s];
        c0 += al * (float)e[0]; c1 += al * (float)e[1];
        c2 += al * (float)e[2]; c3 += al * (float)e[3];
    }
    bfx4 o = {(__bf16)c0, (__bf16)c1, (__bf16)c2, (__bf16)c3};
    *(bfx4*)(&g_Adec[(size_t)b * 1280 + tid * 4]) = o;
}

// ---------------------------------------------------------------------------
extern "C" void kernel_launch(void* const* d_in, const int* in_sizes, int n_in,
                              void* d_out, int out_size, void* d_ws, size_t ws_size,
                              hipStream_t stream)
{
    const int*   source   = (const int*)d_in[0];
    const int*   target   = (const int*)d_in[1];
    const int*   tf       = (const int*)d_in[2];
    const float* emb_src  = (const float*)d_in[3];
    const float* W_ih_enc = (const float*)d_in[4];
    const float* W_hh_enc = (const float*)d_in[5];
    const float* b_ih_enc = (const float*)d_in[6];
    const float* b_hh_enc = (const float*)d_in[7];
    const float* emb_tgt  = (const float*)d_in[8];
    const float* W_attn   = (const float*)d_in[9];
    const float* b_attn   = (const float*)d_in[10];
    const float* v_attn   = (const float*)d_in[11];
    const float* W_ih_dec = (const float*)d_in[12];
    const float* W_hh_dec = (const float*)d_in[13];
    const float* b_ih_dec = (const float*)d_in[14];
    const float* b_hh_dec = (const float*)d_in[15];
    const float* W_out    = (const float*)d_in[16];
    const float* b_out    = (const float*)d_in[17];
    float* out = (float*)d_out;

    void *p_hb, *p_sWhhe, *p_sWihe, *p_sWhhd, *p_sWihd, *p_sWattnA, *p_sWattnB,
         *p_sWout, *p_embs, *p_embt, *p_enc_ops, *p_enc_part;
    hipGetSymbolAddress(&p_hb,       HIP_SYMBOL(g_hb));
    hipGetSymbolAddress(&p_sWhhe,    HIP_SYMBOL(g_sWhhe));
    hipGetSymbolAddress(&p_sWihe,    HIP_SYMBOL(g_sWihe));
    hipGetSymbolAddress(&p_sWhhd,    HIP_SYMBOL(g_sWhhd));
    hipGetSymbolAddress(&p_sWihd,    HIP_SYMBOL(g_sWihd));
    hipGetSymbolAddress(&p_sWattnA,  HIP_SYMBOL(g_sWattnA));
    hipGetSymbolAddress(&p_sWattnB,  HIP_SYMBOL(g_sWattnB));
    hipGetSymbolAddress(&p_sWout,    HIP_SYMBOL(g_sWout));
    hipGetSymbolAddress(&p_embs,     HIP_SYMBOL(g_embs));
    hipGetSymbolAddress(&p_embt,     HIP_SYMBOL(g_embt));
    hipGetSymbolAddress(&p_enc_ops,  HIP_SYMBOL(g_enc_ops));
    hipGetSymbolAddress(&p_enc_part, HIP_SYMBOL(g_enc_part));
    __bf16* hb0 = (__bf16*)p_hb;
    __bf16* hb1 = hb0 + 512 * 1024;

    // ---- one-time setup ----
    k_cvt<<<16, 256, 0, stream>>>(emb_src, (__bf16*)p_embs, 64 * 256 / 4);
    k_cvt<<<18, 256, 0, stream>>>(emb_tgt, (__bf16*)p_embt, 70 * 256 / 4);
    swz_rm<<<1536, 256, 0, stream>>>(W_hh_enc, (__bf16*)p_sWhhe, 32, 393216);
    swz_rm<<<384,  256, 0, stream>>>(W_ih_enc, (__bf16*)p_sWihe, 8,  98304);
    swz_rm<<<1536, 256, 0, stream>>>(W_hh_dec, (__bf16*)p_sWhhd, 32, 393216);
    swz_rm<<<1920, 256, 0, stream>>>(W_ih_dec, (__bf16*)p_sWihd, 40, 491520);
    swz_cm<<<512,  256, 0, stream>>>(W_attn, (__bf16*)p_sWattnA, 32, 1024, 1024, 131072);
    swz_cm<<<512,  256, 0, stream>>>(W_attn + (size_t)1024 * 1024,
                                     (__bf16*)p_sWattnB, 32, 1024, 1024, 131072);
    swz_cm<<<64,   256, 0, stream>>>(W_out,  (__bf16*)p_sWout,   32, 70,   70,   16384);
    k_init<<<2048, 256, 0, stream>>>(out);

    // -------- Encoder: 32 steps --------
    for (int t = 0; t < 32; t++) {
        __bf16* hin  = (t & 1) ? hb1 : hb0;
        __bf16* hout = (t & 1) ? hb0 : hb1;
        gru_step<<<dim3(32, 16), 256, 0, stream>>>(
            hin, hout, (__bf16*)p_sWhhe, b_hh_enc,
            (__bf16*)p_sWihe, b_ih_enc, 8, source + t * 512, t);
    }
    // h_enc lands in hb0

    // enc_part = enc_ops @ W_attn[H:2H]^T  (frag-major weights, no bias)
    k_encpart<<<dim3(1024), 512, 0, stream>>>(
        (__bf16*)p_enc_ops, (__bf16*)p_sWattnB, (__bf16*)p_enc_part);

    // hpart for step 0
    k_hl<<<dim3(18, 16), 256, 0, stream>>>(hb0, b_attn, b_out, -1, out);

    // -------- Decoder: 31 steps --------
    for (int j = 0; j < 31; j++) {
        __bf16* hin  = (j & 1) ? hb1 : hb0;
        __bf16* hout = (j & 1) ? hb0 : hb1;
        k_attn<<<512, 256, 0, stream>>>(j, target, tf, v_attn, out);
        gru_step<<<dim3(32, 16), 256, 0, stream>>>(
            hin, hout, (__bf16*)p_sWhhd, b_hh_dec,
            (__bf16*)p_sWihd, b_ih_dec, 40, nullptr, -1);
        k_hl<<<dim3(18, 16), 256, 0, stream>>>(hout, b_attn, b_out, j + 1, out);
    }
}

// Round 7
// 2087.157 us; speedup vs baseline: 1.3664x; 1.0968x over previous
//
#include <hip/hip_runtime.h>
#include <hip/hip_bf16.h>

typedef __bf16 bfx8 __attribute__((ext_vector_type(8)));
typedef __bf16 bfx4 __attribute__((ext_vector_type(4)));
typedef float f32x4 __attribute__((ext_vector_type(4)));

#define MFMA __builtin_amdgcn_mfma_f32_16x16x32_bf16

// Dims: S=32 T=32 B=512 H=1024 E=256 A=1024 VS=64 VT=70 START=1
// Separate launches (coop grid.sync measured ~35us/sync -- never again).
// Weights pre-swizzled fragment-major. A-operands LDS-staged (R5 proved
// de-staging costs ~+6us/dispatch). k_encpart: XCD-swizzled, LDS C-stage
// (R6: traffic -9%, time-neutral -> fetch-latency bound; frozen).
// NEW (R7): emb-side gi hoisted into vocab-indexed tables --
//   g_tblS[64][3072]  = emb_src @ W_ih_enc^T      (full encoder gi)
//   g_tblT[70][3072]  = emb_tgt @ W_ih_dec[:,H:]^T (decoder gi emb part)
// computed once at setup (vocab is tiny); per-step gru kernels gather
// tbl[x_b][gate*1024+jj] in the epilogue instead of running emb K-frags.
// gru_enc: 4 waves x 16 gh-frags (was 20). gru_dec: 32/32 balanced
// (was 36/36 incl. tail), no acc2.

__device__ __attribute__((aligned(256))) float  g_h[512 * 1024];
__device__ __attribute__((aligned(256))) float  g_hpart[512 * 1024];
__device__ __attribute__((aligned(256))) __bf16 g_hb[2][512 * 1024];
__device__ __attribute__((aligned(256))) __bf16 g_Adec[512 * 1024];
__device__ __attribute__((aligned(256))) __bf16 g_enc_ops[(size_t)32 * 512 * 1024];
__device__ __attribute__((aligned(256))) __bf16 g_enc_part[(size_t)32 * 512 * 1024];
__device__ __attribute__((aligned(256))) __bf16 g_sWhhe[(size_t)3072 * 1024];   // fragment-major
__device__ __attribute__((aligned(256))) __bf16 g_sWihe[(size_t)3072 * 256];
__device__ __attribute__((aligned(256))) __bf16 g_sWhhd[(size_t)3072 * 1024];
__device__ __attribute__((aligned(256))) __bf16 g_sWihd[(size_t)3072 * 1280];
__device__ __attribute__((aligned(256))) __bf16 g_sWattnA[(size_t)1024 * 1024];
__device__ __attribute__((aligned(256))) __bf16 g_sWattnB[(size_t)1024 * 1024]; // W_attn[H:2H] frag-major
__device__ __attribute__((aligned(256))) __bf16 g_sWout[(size_t)128 * 1024];
__device__ __attribute__((aligned(256))) __bf16 g_embs[64 * 256];
__device__ __attribute__((aligned(256))) __bf16 g_embt[96 * 256];   // 70 used; pad for staging
__device__ __attribute__((aligned(256))) float  g_tblS[64 * 3072];
__device__ __attribute__((aligned(256))) float  g_tblT[70 * 3072];
__device__ __attribute__((aligned(256))) int    g_xsel[512];

__device__ __forceinline__ float fast_tanh(float x) {
    float cx = fminf(fmaxf(x, -15.f), 15.f);
    float e = __expf(-2.f * cx);
    return (1.f - e) / (1.f + e);
}

// ---------------------------------------------------------------------------
__global__ void k_cvt(const float* __restrict__ src, __bf16* __restrict__ dst,
                      int n4)
{
    int i = blockIdx.x * 256 + threadIdx.x;
    if (i >= n4) return;
    float4 v = ((const float4*)src)[i];
    __bf16 o[4] = {(__bf16)v.x, (__bf16)v.y, (__bf16)v.z, (__bf16)v.w};
    *(ushort2*)(dst + 4 * i) = *(ushort2*)o;
    *(ushort2*)(dst + 4 * i + 2) = *(ushort2*)(o + 2);
}

// Row-major f32 W[R][K] -> fragment-major bf16.
__global__ void swz_rm(const float* __restrict__ W, __bf16* __restrict__ out,
                       int nK, int total)
{
    int gid = blockIdx.x * 256 + threadIdx.x;
    if (gid >= total) return;
    int F = gid >> 6, L = gid & 63;
    int t = F / nK, c = F - t * nK;
    int K = nK * 32;
    const float* s = W + (size_t)(t * 16 + (L & 15)) * K + c * 32 + (L >> 4) * 8;
    __bf16 o[8];
#pragma unroll
    for (int u = 0; u < 8; u++) o[u] = (__bf16)s[u];
    *(uint4*)(out + (size_t)gid * 8) = *(uint4*)o;
}

// Column-gather: logical W'[n][k] = W[k*ldsrc + n]; n>=nguard -> 0.
__global__ void swz_cm(const float* __restrict__ W, __bf16* __restrict__ out,
                       int nK, int ldsrc, int nguard, int total)
{
    int gid = blockIdx.x * 256 + threadIdx.x;
    if (gid >= total) return;
    int F = gid >> 6, L = gid & 63;
    int t = F / nK, c = F - t * nK;
    int n = t * 16 + (L & 15);
    int k = c * 32 + (L >> 4) * 8;
    __bf16 o[8];
#pragma unroll
    for (int u = 0; u < 8; u++)
        o[u] = (n < nguard) ? (__bf16)W[(size_t)(k + u) * ldsrc + n] : (__bf16)0.f;
    *(uint4*)(out + (size_t)gid * 8) = *(uint4*)o;
}

__global__ void k_init(float* __restrict__ out)
{
    int idx = blockIdx.x * 256 + threadIdx.x;
    if (idx < 512 * 1024) { g_h[idx] = 0.f; g_hb[0][idx] = (__bf16)0.f; }
    if (idx < 512 * 70) out[idx] = (idx % 70 == 1) ? 1.f : 0.f;
}

// ---------------------------------------------------------------------------
// k_tbl: tbl[v][n] = emb[v][:] . W[n][cOff*32 : cOff*32+256]  (K=256, 8 frags)
// grid (48 n-tiles x64, m-tiles x32). sW fragment-major with nKtot frags/row;
// frags cOff..cOff+7 used. Output f32, rows guarded to vguard.
// ---------------------------------------------------------------------------
__global__ __launch_bounds__(256) void k_tbl(
    const __bf16* __restrict__ emb, const __bf16* __restrict__ sW,
    int nKtot, int cOff, int vguard, float* __restrict__ tbl)
{
    __shared__ __bf16 sA[32 * 256];
    const int tid = threadIdx.x;
    const int w = tid >> 6, lane = tid & 63;
    const int r15 = lane & 15, q = lane >> 4;
    const int bx = blockIdx.x, m0 = blockIdx.y * 32;

#pragma unroll
    for (int i = 0; i < 4; i++) {
        int lin = tid + i * 256;
        int r = lin >> 5, U = lin & 31;
        uint4 v = *(const uint4*)(emb + (size_t)(m0 + r) * 256 + U * 8);
        *(uint4*)(sA + (r * 32 + (U ^ (r & 7))) * 8) = v;
    }
    __syncthreads();

    const size_t tb = (size_t)(bx * 4 + w);
    const __bf16* wp = sW + (tb * nKtot + cOff) * 512 + lane * 8;
    const int xk = r15 & 7;
    const int ar0 = r15 * 256, ar1 = (16 + r15) * 256;

    f32x4 acc[2];
    acc[0] = (f32x4){0.f, 0.f, 0.f, 0.f};
    acc[1] = (f32x4){0.f, 0.f, 0.f, 0.f};
#pragma unroll
    for (int c = 0; c < 8; c++) {
        int us = ((c * 4 + q) ^ xk) * 8;
        bfx8 a0 = *(const bfx8*)(sA + ar0 + us);
        bfx8 a1 = *(const bfx8*)(sA + ar1 + us);
        bfx8 wv = *(const bfx8*)(wp + c * 512);
        acc[0] = MFMA(a0, wv, acc[0], 0, 0, 0);
        acc[1] = MFMA(a1, wv, acc[1], 0, 0, 0);
    }
    const int n = bx * 64 + w * 16 + r15;
#pragma unroll
    for (int ms = 0; ms < 2; ms++)
#pragma unroll
        for (int reg = 0; reg < 4; reg++) {
            int row = m0 + ms * 16 + q * 4 + reg;
            if (row < vguard)
                tbl[(size_t)row * 3072 + n] = acc[ms][reg];
        }
}

// ---------------------------------------------------------------------------
// k_encpart (frozen R6): XCD-swizzled, A dbuf 32KB K-chunks, LDS C-stage.
// ---------------------------------------------------------------------------
__global__ __launch_bounds__(512, 4) void k_encpart(
    const __bf16* __restrict__ Amat, const __bf16* __restrict__ sW,
    __bf16* __restrict__ Cout)
{
    __shared__ __bf16 sA[2][64 * 256];   // 2 x 32 KB
    const int tid = threadIdx.x;
    const int w = tid >> 6, lane = tid & 63;
    const int r15 = lane & 15, q = lane >> 4;
    const int sw = (blockIdx.x & 7) * 128 + (blockIdx.x >> 3);
    const int nx = sw & 3;
    const int n0 = nx * 256, m0 = (sw >> 2) * 64;

    int sr[4], sv[4], so[4];
#pragma unroll
    for (int i = 0; i < 4; i++) {
        int lin = tid + i * 512;
        sr[i] = lin >> 5;
        sv[i] = lin & 31;
        so[i] = (sr[i] * 32 + (sv[i] ^ (sr[i] & 7))) * 8;
    }

    uint4 regs[4];
#pragma unroll
    for (int i = 0; i < 4; i++)
        regs[i] = *(const uint4*)(Amat + (size_t)(m0 + sr[i]) * 1024 + sv[i] * 8);
#pragma unroll
    for (int i = 0; i < 4; i++)
        *(uint4*)(&sA[0][so[i]]) = regs[i];
    __syncthreads();

    const int xk = r15 & 7;
    f32x4 acc[2][4];
#pragma unroll
    for (int nn = 0; nn < 2; nn++)
#pragma unroll
        for (int mf = 0; mf < 4; mf++) acc[nn][mf] = (f32x4){0.f, 0.f, 0.f, 0.f};

    const __bf16* wp0 = sW + ((size_t)(nx * 16 + w * 2) * 32) * 512 + lane * 8;
    const __bf16* wp1 = wp0 + 32 * 512;
    const int ar0 = r15 * 256;
    const int ar1 = (16 + r15) * 256;
    const int ar2 = (32 + r15) * 256;
    const int ar3 = (48 + r15) * 256;

    for (int kc = 0; kc < 4; kc++) {
        if (kc < 3) {
#pragma unroll
            for (int i = 0; i < 4; i++)
                regs[i] = *(const uint4*)(Amat + (size_t)(m0 + sr[i]) * 1024 +
                                          (kc + 1) * 256 + sv[i] * 8);
        }
        const __bf16* sAb = sA[kc & 1];
        const __bf16* wq0 = wp0 + kc * 8 * 512;
        const __bf16* wq1 = wp1 + kc * 8 * 512;
#pragma unroll
        for (int c = 0; c < 8; c++) {
            int us = ((c * 4 + q) ^ xk) * 8;
            bfx8 a0 = *(const bfx8*)(sAb + ar0 + us);
            bfx8 a1 = *(const bfx8*)(sAb + ar1 + us);
            bfx8 a2 = *(const bfx8*)(sAb + ar2 + us);
            bfx8 a3 = *(const bfx8*)(sAb + ar3 + us);
            bfx8 w0 = *(const bfx8*)(wq0 + c * 512);
            bfx8 w1 = *(const bfx8*)(wq1 + c * 512);
            acc[0][0] = MFMA(a0, w0, acc[0][0], 0, 0, 0);
            acc[0][1] = MFMA(a1, w0, acc[0][1], 0, 0, 0);
            acc[0][2] = MFMA(a2, w0, acc[0][2], 0, 0, 0);
            acc[0][3] = MFMA(a3, w0, acc[0][3], 0, 0, 0);
            acc[1][0] = MFMA(a0, w1, acc[1][0], 0, 0, 0);
            acc[1][1] = MFMA(a1, w1, acc[1][1], 0, 0, 0);
            acc[1][2] = MFMA(a2, w1, acc[1][2], 0, 0, 0);
            acc[1][3] = MFMA(a3, w1, acc[1][3], 0, 0, 0);
        }
        if (kc < 3) {
#pragma unroll
            for (int i = 0; i < 4; i++)
                *(uint4*)(&sA[(kc + 1) & 1][so[i]]) = regs[i];
            __syncthreads();
        }
    }

    __bf16* sC = sA[0];
#pragma unroll
    for (int nn = 0; nn < 2; nn++) {
        const int cl = (w * 2 + nn) * 16 + r15;
#pragma unroll
        for (int mf = 0; mf < 4; mf++) {
#pragma unroll
            for (int reg = 0; reg < 4; reg++) {
                int row = mf * 16 + q * 4 + reg;
                sC[row * 256 + cl] = (__bf16)acc[nn][mf][reg];
            }
        }
    }
    __syncthreads();
#pragma unroll
    for (int i = 0; i < 4; i++) {
        int lin = tid + i * 512;
        int row = lin >> 5, unit = lin & 31;
        *(uint4*)(Cout + (size_t)(m0 + row) * 1024 + n0 + unit * 8) =
            *(const uint4*)(sC + row * 256 + unit * 8);
    }
}

// ---------------------------------------------------------------------------
#define GH_BODY(ACC)                                              \
    {                                                             \
        int us = ((c * 4 + q) ^ xk) * 8;                          \
        bfx8 a0 = *(const bfx8*)(sA1 + br0 + us);                 \
        bfx8 a1 = *(const bfx8*)(sA1 + br1 + us);                 \
        bfx8 w0 = *(const bfx8*)(xp0 + c * 512);                  \
        bfx8 w1 = *(const bfx8*)(xp1 + c * 512);                  \
        bfx8 w2 = *(const bfx8*)(xp2 + c * 512);                  \
        ACC[0][0] = MFMA(a0, w0, ACC[0][0], 0, 0, 0);             \
        ACC[0][1] = MFMA(a1, w0, ACC[0][1], 0, 0, 0);             \
        ACC[1][0] = MFMA(a0, w1, ACC[1][0], 0, 0, 0);             \
        ACC[1][1] = MFMA(a1, w1, ACC[1][1], 0, 0, 0);             \
        ACC[2][0] = MFMA(a0, w2, ACC[2][0], 0, 0, 0);             \
        ACC[2][1] = MFMA(a1, w2, ACC[2][1], 0, 0, 0);             \
    }

#define GI_BODY(ACC)                                              \
    {                                                             \
        bfx8 a0 = *(const bfx8*)(A0 + c * 32);                    \
        bfx8 a1 = *(const bfx8*)(A1 + c * 32);                    \
        bfx8 w0 = *(const bfx8*)(wp0 + c * 512);                  \
        bfx8 w1 = *(const bfx8*)(wp1 + c * 512);                  \
        bfx8 w2 = *(const bfx8*)(wp2 + c * 512);                  \
        ACC[0][0] = MFMA(a0, w0, ACC[0][0], 0, 0, 0);             \
        ACC[0][1] = MFMA(a1, w0, ACC[0][1], 0, 0, 0);             \
        ACC[1][0] = MFMA(a0, w1, ACC[1][0], 0, 0, 0);             \
        ACC[1][1] = MFMA(a1, w1, ACC[1][1], 0, 0, 0);             \
        ACC[2][0] = MFMA(a0, w2, ACC[2][0], 0, 0, 0);             \
        ACC[2][1] = MFMA(a1, w2, ACC[2][1], 0, 0, 0);             \
    }

// ---------------------------------------------------------------------------
// gru_enc: h' from h. grid (32 j, 16 m) x 256 thr. gi comes from g_tblS
// (epilogue gather). All 4 waves run gh: w0/w2 jsub per w&1, c-split
// [0,16)/[16,32); w>=2 partial -> sGh handoff. LDS 76KB -> 2 blocks/CU.
// ---------------------------------------------------------------------------
__global__ __launch_bounds__(256, 2) void gru_enc(
    const __bf16* __restrict__ hb_in, __bf16* __restrict__ hb_out,
    const float* __restrict__ b1, const float* __restrict__ b2,
    const int* __restrict__ src_t, int enc_t)
{
    __shared__ __align__(16) unsigned char smem[77824];
    __bf16* sA1 = (__bf16*)smem;            // 64 KB
    float*  sGh = (float*)(smem + 65536);   // 12 KB
    const int tid = threadIdx.x;
    const int w = tid >> 6, lane = tid & 63;
    const int r15 = lane & 15, q = lane >> 4;
    const int j0 = blockIdx.x * 32, m0 = blockIdx.y * 32;
    const int jsub = w & 1;

#pragma unroll
    for (int i = 0; i < 16; i++) {
        int lin = tid + i * 256;
        int r = lin >> 7, U = lin & 127;
        uint4 v = *(const uint4*)(hb_in + (size_t)(m0 + r) * 1024 + U * 8);
        *(uint4*)(sA1 + (r * 128 + (U ^ (r & 7))) * 8) = v;
    }
    __syncthreads();

    const size_t tb = (size_t)(blockIdx.x * 2 + jsub);
    const int xk = r15 & 7;
    f32x4 acc[3][2];
#pragma unroll
    for (int s = 0; s < 3; s++)
#pragma unroll
        for (int ms = 0; ms < 2; ms++) acc[s][ms] = (f32x4){0.f, 0.f, 0.f, 0.f};

    const __bf16* xp0 = g_sWhhe + (tb * 32) * 512 + lane * 8;
    const __bf16* xp1 = g_sWhhe + ((tb + 64) * 32) * 512 + lane * 8;
    const __bf16* xp2 = g_sWhhe + ((tb + 128) * 32) * 512 + lane * 8;
    const int br0 = r15 * 1024, br1 = (16 + r15) * 1024;
    const int cbeg = (w < 2) ? 0 : 16;
#pragma unroll 8
    for (int c = cbeg; c < cbeg + 16; c++) GH_BODY(acc)

    if (w >= 2) {
#pragma unroll
        for (int s = 0; s < 3; s++)
#pragma unroll
            for (int ms = 0; ms < 2; ms++)
#pragma unroll
                for (int reg = 0; reg < 4; reg++)
                    sGh[((s * 2 + jsub) * 32 + ms * 16 + q * 4 + reg) * 16 + r15] =
                        acc[s][ms][reg];
    }
    __syncthreads();
    if (w < 2) {
        const int jj = j0 + jsub * 16 + r15;
        const float bb1[3] = {b1[jj], b1[1024 + jj], b1[2048 + jj]};
        const float bb2[3] = {b2[jj], b2[1024 + jj], b2[2048 + jj]};
#pragma unroll
        for (int ms = 0; ms < 2; ms++) {
#pragma unroll
            for (int reg = 0; reg < 4; reg++) {
                int bl = ms * 16 + q * 4 + reg;
                int b_ = m0 + bl;
                int xv = src_t[b_];
                xv = (xv < 0) ? 0 : (xv > 63 ? 63 : xv);
                const float* tv = g_tblS + (size_t)xv * 3072 + jj;
                float gh0 = acc[0][ms][reg] + bb1[0] +
                            sGh[((0 * 2 + jsub) * 32 + bl) * 16 + r15];
                float gh1 = acc[1][ms][reg] + bb1[1] +
                            sGh[((1 * 2 + jsub) * 32 + bl) * 16 + r15];
                float gh2 = acc[2][ms][reg] + bb1[2] +
                            sGh[((2 * 2 + jsub) * 32 + bl) * 16 + r15];
                float gi0 = tv[0]    + bb2[0];
                float gi1 = tv[1024] + bb2[1];
                float gi2 = tv[2048] + bb2[2];
                float r = 1.f / (1.f + __expf(-(gi0 + gh0)));
                float z = 1.f / (1.f + __expf(-(gi1 + gh1)));
                float n = fast_tanh(gi2 + r * gh2);
                size_t off = (size_t)b_ * 1024 + jj;
                float hv = (1.f - z) * n + z * g_h[off];
                g_h[off] = hv;
                hb_out[off] = (__bf16)hv;
                g_enc_ops[(size_t)enc_t * 524288 + off] = (__bf16)hv;
            }
        }
    }
}

// ---------------------------------------------------------------------------
// gru_dec: waves 0-1 gh (32 frags, LDS-staged h), waves 2-3 gi ctx-part
// (32 frags, Adec direct) -> sGi handoff. Emb part of gi gathered from
// g_tblT[g_xsel[b]] in the epilogue. Balanced 32/32.
// ---------------------------------------------------------------------------
__global__ __launch_bounds__(256, 2) void gru_dec(
    const __bf16* __restrict__ hb_in, __bf16* __restrict__ hb_out,
    const float* __restrict__ b1, const float* __restrict__ b2)
{
    __shared__ __align__(16) unsigned char smem[77824];
    __bf16* sA1 = (__bf16*)smem;            // 64 KB
    float*  sGi = (float*)(smem + 65536);   // 12 KB
    const int tid = threadIdx.x;
    const int w = tid >> 6, lane = tid & 63;
    const int r15 = lane & 15, q = lane >> 4;
    const int j0 = blockIdx.x * 32, m0 = blockIdx.y * 32;
    const int jsub = w & 1;

#pragma unroll
    for (int i = 0; i < 16; i++) {
        int lin = tid + i * 256;
        int r = lin >> 7, U = lin & 127;
        uint4 v = *(const uint4*)(hb_in + (size_t)(m0 + r) * 1024 + U * 8);
        *(uint4*)(sA1 + (r * 128 + (U ^ (r & 7))) * 8) = v;
    }
    __syncthreads();

    const size_t tb = (size_t)(blockIdx.x * 2 + jsub);
    const int xk = r15 & 7;
    f32x4 acc[3][2];
#pragma unroll
    for (int s = 0; s < 3; s++)
#pragma unroll
        for (int ms = 0; ms < 2; ms++) acc[s][ms] = (f32x4){0.f, 0.f, 0.f, 0.f};

    if (w < 2) {
        const __bf16* xp0 = g_sWhhd + (tb * 32) * 512 + lane * 8;
        const __bf16* xp1 = g_sWhhd + ((tb + 64) * 32) * 512 + lane * 8;
        const __bf16* xp2 = g_sWhhd + ((tb + 128) * 32) * 512 + lane * 8;
        const int br0 = r15 * 1024, br1 = (16 + r15) * 1024;
#pragma unroll 8
        for (int c = 0; c < 32; c++) GH_BODY(acc)
    } else {
        const __bf16* A0 = g_Adec + (size_t)(m0 + r15) * 1024 + q * 8;
        const __bf16* A1 = A0 + 16 * 1024;
        const __bf16* wp0 = g_sWihd + (tb * 40) * 512 + lane * 8;
        const __bf16* wp1 = g_sWihd + ((tb + 64) * 40) * 512 + lane * 8;
        const __bf16* wp2 = g_sWihd + ((tb + 128) * 40) * 512 + lane * 8;
#pragma unroll 8
        for (int c = 0; c < 32; c++) GI_BODY(acc)
#pragma unroll
        for (int s = 0; s < 3; s++)
#pragma unroll
            for (int ms = 0; ms < 2; ms++)
#pragma unroll
                for (int reg = 0; reg < 4; reg++)
                    sGi[((s * 2 + jsub) * 32 + ms * 16 + q * 4 + reg) * 16 + r15] =
                        acc[s][ms][reg];
    }
    __syncthreads();
    if (w < 2) {
        const int jj = j0 + jsub * 16 + r15;
        const float bb1[3] = {b1[jj], b1[1024 + jj], b1[2048 + jj]};
        const float bb2[3] = {b2[jj], b2[1024 + jj], b2[2048 + jj]};
#pragma unroll
        for (int ms = 0; ms < 2; ms++) {
#pragma unroll
            for (int reg = 0; reg < 4; reg++) {
                int bl = ms * 16 + q * 4 + reg;
                int b_ = m0 + bl;
                const float* tv = g_tblT + (size_t)g_xsel[b_] * 3072 + jj;
                float gh0 = acc[0][ms][reg] + bb1[0];
                float gh1 = acc[1][ms][reg] + bb1[1];
                float gh2 = acc[2][ms][reg] + bb1[2];
                float gi0 = sGi[((0 * 2 + jsub) * 32 + bl) * 16 + r15] +
                            tv[0]    + bb2[0];
                float gi1 = sGi[((1 * 2 + jsub) * 32 + bl) * 16 + r15] +
                            tv[1024] + bb2[1];
                float gi2 = sGi[((2 * 2 + jsub) * 32 + bl) * 16 + r15] +
                            tv[2048] + bb2[2];
                float r = 1.f / (1.f + __expf(-(gi0 + gh0)));
                float z = 1.f / (1.f + __expf(-(gi1 + gh1)));
                float n = fast_tanh(gi2 + r * gh2);
                size_t off = (size_t)b_ * 1024 + jj;
                float hv = (1.f - z) * n + z * g_h[off];
                g_h[off] = hv;
                hb_out[off] = (__bf16)hv;
            }
        }
    }
}

// ---------------------------------------------------------------------------
// Fused [hpart | logits] from h (bf16). grid (18, 16). bx<16: hpart col-tile;
// bx 16..17: logits (guard 70) -> out row lrow (skipped if lrow<0).
// ---------------------------------------------------------------------------
__global__ __launch_bounds__(256) void k_hl(
    const __bf16* __restrict__ src, const float* __restrict__ battn,
    const float* __restrict__ bout, int lrow, float* __restrict__ outp)
{
    __shared__ __bf16 sA[32 * 1024];
    const int tid = threadIdx.x;
    const int w = tid >> 6, lane = tid & 63;
    const int r15 = lane & 15, q = lane >> 4;
    const int bx = blockIdx.x, m0 = blockIdx.y * 32;

#pragma unroll
    for (int i = 0; i < 16; i++) {
        int lin = tid + i * 256;
        int r = lin >> 7, U = lin & 127;
        uint4 v = *(const uint4*)(src + (size_t)(m0 + r) * 1024 + U * 8);
        *(uint4*)(sA + (r * 128 + (U ^ (r & 7))) * 8) = v;
    }
    __syncthreads();

    const __bf16* sW;
    int n;
    if (bx < 16) {
        sW = g_sWattnA;
        n = bx * 64 + w * 16 + r15;
    } else {
        if (lrow < 0) return;
        sW = g_sWout;
        n = (bx - 16) * 64 + w * 16 + r15;
    }
    const size_t tb = (size_t)((bx < 16 ? bx : bx - 16) * 4 + w);
    const __bf16* wp = sW + (tb * 32) * 512 + lane * 8;
    const int xk = r15 & 7;
    const int ar0 = r15 * 1024, ar1 = (16 + r15) * 1024;

    f32x4 acc[2];
    acc[0] = (f32x4){0.f, 0.f, 0.f, 0.f};
    acc[1] = (f32x4){0.f, 0.f, 0.f, 0.f};
#pragma unroll 8
    for (int c = 0; c < 32; c++) {
        int us = ((c * 4 + q) ^ xk) * 8;
        bfx8 a0 = *(const bfx8*)(sA + ar0 + us);
        bfx8 a1 = *(const bfx8*)(sA + ar1 + us);
        bfx8 wv = *(const bfx8*)(wp + c * 512);
        acc[0] = MFMA(a0, wv, acc[0], 0, 0, 0);
        acc[1] = MFMA(a1, wv, acc[1], 0, 0, 0);
    }

    if (bx < 16) {
        float bv = battn[n];
#pragma unroll
        for (int ms = 0; ms < 2; ms++)
#pragma unroll
            for (int reg = 0; reg < 4; reg++)
                g_hpart[(size_t)(m0 + ms * 16 + q * 4 + reg) * 1024 + n] =
                    acc[ms][reg] + bv;
    } else if (n < 70) {
        float bv = bout[n];
#pragma unroll
        for (int ms = 0; ms < 2; ms++)
#pragma unroll
            for (int reg = 0; reg < 4; reg++)
                outp[(size_t)lrow * 35840 +
                     (size_t)(m0 + ms * 16 + q * 4 + reg) * 70 + n] =
                    acc[ms][reg] + bv;
    }
}

// ---------------------------------------------------------------------------
// Attention step: x-select (-> g_xsel) + scores + softmax + alpha out + ctx.
// One block per batch b.
// ---------------------------------------------------------------------------
__global__ __launch_bounds__(256) void k_attn(
    int j, const int* __restrict__ target, const int* __restrict__ tf,
    const float* __restrict__ v_attn, float* __restrict__ out)
{
    const int b = blockIdx.x, tid = threadIdx.x;
    const int lane = tid & 63, wave = tid >> 6;
    __shared__ float sc[32], sal[32];
    __shared__ int sx;
    if (wave == 0) {
        int xv;
        if (j == 0) xv = target[b];
        else if (*tf) xv = target[j * 512 + b];
        else {
            const float* row = out + (size_t)j * 35840 + b * 70;
            float bv = row[lane]; int bi = lane;
            if (lane < 6) {
                float v2 = row[lane + 64];
                if (v2 > bv) { bv = v2; bi = lane + 64; }
            }
#pragma unroll
            for (int off = 32; off; off >>= 1) {
                float ov = __shfl_down(bv, off);
                int   oi = __shfl_down(bi, off);
                if (ov > bv || (ov == bv && oi < bi)) { bv = ov; bi = oi; }
            }
            xv = bi;
        }
        if (lane == 0) sx = (xv < 0) ? 0 : (xv > 69 ? 69 : xv);
    }
    float hpv[16], vsv[16];
    {
        const float* hp = g_hpart + (size_t)b * 1024;
#pragma unroll
        for (int u = 0; u < 8; u++) {
            hpv[u]     = hp[lane * 8 + u];
            hpv[8 + u] = hp[512 + lane * 8 + u];
            vsv[u]     = v_attn[lane * 8 + u];
            vsv[8 + u] = v_attn[512 + lane * 8 + u];
        }
    }
    __syncthreads();
    if (tid == 0) g_xsel[b] = sx;
    for (int s = wave * 8; s < wave * 8 + 8; s++) {
        const __bf16* ep = g_enc_part + ((size_t)s * 512 + b) * 1024;
        bfx8 e0 = *(const bfx8*)(ep + lane * 8);
        bfx8 e1 = *(const bfx8*)(ep + 512 + lane * 8);
        float part = 0.f;
#pragma unroll
        for (int u = 0; u < 8; u++) {
            part += vsv[u]     * fast_tanh((float)e0[u] + hpv[u]);
            part += vsv[8 + u] * fast_tanh((float)e1[u] + hpv[8 + u]);
        }
#pragma unroll
        for (int off = 32; off; off >>= 1) part += __shfl_down(part, off);
        if (lane == 0) sc[s] = part;
    }
    __syncthreads();
    float mx = sc[0];
#pragma unroll
    for (int s = 1; s < 32; s++) mx = fmaxf(mx, sc[s]);
    float den = 0.f;
#pragma unroll
    for (int s = 0; s < 32; s++) den += __expf(sc[s] - mx);
    float rden = 1.f / den;
    if (tid < 32) {
        float al = __expf(sc[tid] - mx) * rden;
        sal[tid] = al;
        out[1146880 + (size_t)j * 16384 + b * 32 + tid] = al;
    }
    __syncthreads();
    float c0 = 0, c1 = 0, c2 = 0, c3 = 0;
    const __bf16* eo = g_enc_ops + (size_t)b * 1024 + tid * 4;
#pragma unroll 4
    for (int s = 0; s < 32; s++) {
        bfx4 e = *(const bfx4*)(eo + (size_t)s * 524288);
        float al = sal[s];
        c0 += al * (float)e[0]; c1 += al * (float)e[1];
        c2 += al * (float)e[2]; c3 += al * (float)e[3];
    }
    bfx4 o = {(__bf16)c0, (__bf16)c1, (__bf16)c2, (__bf16)c3};
    *(bfx4*)(&g_Adec[(size_t)b * 1024 + tid * 4]) = o;
}

// ---------------------------------------------------------------------------
extern "C" void kernel_launch(void* const* d_in, const int* in_sizes, int n_in,
                              void* d_out, int out_size, void* d_ws, size_t ws_size,
                              hipStream_t stream)
{
    const int*   source   = (const int*)d_in[0];
    const int*   target   = (const int*)d_in[1];
    const int*   tf       = (const int*)d_in[2];
    const float* emb_src  = (const float*)d_in[3];
    const float* W_ih_enc = (const float*)d_in[4];
    const float* W_hh_enc = (const float*)d_in[5];
    const float* b_ih_enc = (const float*)d_in[6];
    const float* b_hh_enc = (const float*)d_in[7];
    const float* emb_tgt  = (const float*)d_in[8];
    const float* W_attn   = (const float*)d_in[9];
    const float* b_attn   = (const float*)d_in[10];
    const float* v_attn   = (const float*)d_in[11];
    const float* W_ih_dec = (const float*)d_in[12];
    const float* W_hh_dec = (const float*)d_in[13];
    const float* b_ih_dec = (const float*)d_in[14];
    const float* b_hh_dec = (const float*)d_in[15];
    const float* W_out    = (const float*)d_in[16];
    const float* b_out    = (const float*)d_in[17];
    float* out = (float*)d_out;

    void *p_hb, *p_sWhhe, *p_sWihe, *p_sWhhd, *p_sWihd, *p_sWattnA, *p_sWattnB,
         *p_sWout, *p_embs, *p_embt, *p_enc_ops, *p_enc_part, *p_tblS, *p_tblT;
    hipGetSymbolAddress(&p_hb,       HIP_SYMBOL(g_hb));
    hipGetSymbolAddress(&p_sWhhe,    HIP_SYMBOL(g_sWhhe));
    hipGetSymbolAddress(&p_sWihe,    HIP_SYMBOL(g_sWihe));
    hipGetSymbolAddress(&p_sWhhd,    HIP_SYMBOL(g_sWhhd));
    hipGetSymbolAddress(&p_sWihd,    HIP_SYMBOL(g_sWihd));
    hipGetSymbolAddress(&p_sWattnA,  HIP_SYMBOL(g_sWattnA));
    hipGetSymbolAddress(&p_sWattnB,  HIP_SYMBOL(g_sWattnB));
    hipGetSymbolAddress(&p_sWout,    HIP_SYMBOL(g_sWout));
    hipGetSymbolAddress(&p_embs,     HIP_SYMBOL(g_embs));
    hipGetSymbolAddress(&p_embt,     HIP_SYMBOL(g_embt));
    hipGetSymbolAddress(&p_enc_ops,  HIP_SYMBOL(g_enc_ops));
    hipGetSymbolAddress(&p_enc_part, HIP_SYMBOL(g_enc_part));
    hipGetSymbolAddress(&p_tblS,     HIP_SYMBOL(g_tblS));
    hipGetSymbolAddress(&p_tblT,     HIP_SYMBOL(g_tblT));
    __bf16* hb0 = (__bf16*)p_hb;
    __bf16* hb1 = hb0 + 512 * 1024;

    // ---- one-time setup ----
    k_cvt<<<16, 256, 0, stream>>>(emb_src, (__bf16*)p_embs, 64 * 256 / 4);
    k_cvt<<<18, 256, 0, stream>>>(emb_tgt, (__bf16*)p_embt, 70 * 256 / 4);
    swz_rm<<<1536, 256, 0, stream>>>(W_hh_enc, (__bf16*)p_sWhhe, 32, 393216);
    swz_rm<<<384,  256, 0, stream>>>(W_ih_enc, (__bf16*)p_sWihe, 8,  98304);
    swz_rm<<<1536, 256, 0, stream>>>(W_hh_dec, (__bf16*)p_sWhhd, 32, 393216);
    swz_rm<<<1920, 256, 0, stream>>>(W_ih_dec, (__bf16*)p_sWihd, 40, 491520);
    swz_cm<<<512,  256, 0, stream>>>(W_attn, (__bf16*)p_sWattnA, 32, 1024, 1024, 131072);
    swz_cm<<<512,  256, 0, stream>>>(W_attn + (size_t)1024 * 1024,
                                     (__bf16*)p_sWattnB, 32, 1024, 1024, 131072);
    swz_cm<<<64,   256, 0, stream>>>(W_out,  (__bf16*)p_sWout,   32, 70,   70,   16384);
    // gi tables: tblS = emb_src @ W_ih_enc^T ; tblT = emb_tgt @ W_ih_dec[:,H:]^T
    k_tbl<<<dim3(48, 2), 256, 0, stream>>>(
        (__bf16*)p_embs, (__bf16*)p_sWihe, 8,  0,  64, (float*)p_tblS);
    k_tbl<<<dim3(48, 3), 256, 0, stream>>>(
        (__bf16*)p_embt, (__bf16*)p_sWihd, 40, 32, 70, (float*)p_tblT);
    k_init<<<2048, 256, 0, stream>>>(out);

    // -------- Encoder: 32 steps --------
    for (int t = 0; t < 32; t++) {
        __bf16* hin  = (t & 1) ? hb1 : hb0;
        __bf16* hout = (t & 1) ? hb0 : hb1;
        gru_enc<<<dim3(32, 16), 256, 0, stream>>>(
            hin, hout, b_hh_enc, b_ih_enc, source + t * 512, t);
    }
    // h_enc lands in hb0

    // enc_part = enc_ops @ W_attn[H:2H]^T  (frag-major weights, no bias)
    k_encpart<<<dim3(1024), 512, 0, stream>>>(
        (__bf16*)p_enc_ops, (__bf16*)p_sWattnB, (__bf16*)p_enc_part);

    // hpart for step 0
    k_hl<<<dim3(18, 16), 256, 0, stream>>>(hb0, b_attn, b_out, -1, out);

    // -------- Decoder: 31 steps --------
    for (int j = 0; j < 31; j++) {
        __bf16* hin  = (j & 1) ? hb1 : hb0;
        __bf16* hout = (j & 1) ? hb0 : hb1;
        k_attn<<<512, 256, 0, stream>>>(j, target, tf, v_attn, out);
        gru_dec<<<dim3(32, 16), 256, 0, stream>>>(hin, hout, b_hh_dec, b_ih_dec);
        k_hl<<<dim3(18, 16), 256, 0, stream>>>(hout, b_attn, b_out, j + 1, out);
    }
}